// Round 8
// baseline (285.156 us; speedup 1.0000x reference)
//
#include <hip/hip_runtime.h>

#define N_  30000
#define E_  480000

typedef short short8 __attribute__((ext_vector_type(8)));
typedef float f32x4  __attribute__((ext_vector_type(4)));
typedef float f32x2  __attribute__((ext_vector_type(2)));
typedef unsigned int u32x4 __attribute__((ext_vector_type(4)));
typedef unsigned int u32x2 __attribute__((ext_vector_type(2)));
typedef int i32x4 __attribute__((ext_vector_type(4)));
union Frag { u32x4 q; short8 v; unsigned short us[8]; };

__device__ __forceinline__ float b2f(unsigned short u){
  union { unsigned int i; float f; } v; v.i = ((unsigned int)u) << 16; return v.f;
}
__device__ __forceinline__ float blo(unsigned int u){
  union { unsigned int i; float f; } v; v.i = u << 16; return v.f;
}
__device__ __forceinline__ float bhi(unsigned int u){
  union { unsigned int i; float f; } v; v.i = u & 0xffff0000u; return v.f;
}
__device__ __forceinline__ unsigned short f2b(float f){
  union { float f; unsigned int u; } v; v.f = f;
  unsigned int u = v.u;
  return (unsigned short)((u + 0x7fffu + ((u >> 16) & 1u)) >> 16);
}
// direct global->LDS 16B copy (dest = wave-uniform base + lane*16)
__device__ __forceinline__ void gl_lds16(const unsigned short* g, unsigned short* l){
  __builtin_amdgcn_global_load_lds(
      (const __attribute__((address_space(1))) unsigned int*)g,
      (__attribute__((address_space(3))) unsigned int*)l, 16, 0, 0);
}

// ---- init scratch + PRE-SWIZZLED weight LDS-images + P fold ----
__global__ void k_initconv(const float* __restrict__ Wfc, const float* __restrict__ Wres,
                           const float* __restrict__ Wout,
                           const float* __restrict__ al, const float* __restrict__ ar,
                           unsigned short* __restrict__ Wt2s, unsigned short* __restrict__ WtOuts,
                           float* __restrict__ P,
                           int* __restrict__ counts, int* __restrict__ cursor){
  int bx = blockIdx.x;
  if (bx >= 256){
    int idx = (bx - 256) * 256 + threadIdx.x;   // 0..1023
    if (idx < 1024){
      int k = idx >> 3, q = idx & 7;
      int h = q & 3;
      const float* a = (q < 4) ? al : ar;
      const float* wr = Wfc + k * 512 + h * 128;
      const float* av = a + h * 128;
      float s = 0.f;
#pragma unroll 4
      for (int d = 0; d < 128; d++) s += wr[d] * av[d];
      P[k * 8 + q] = s;
    }
    return;
  }
  int gid = bx * 256 + threadIdx.x;
  const int stride = 256 * 256;
  if (gid < N_){ counts[gid] = 0; cursor[gid] = 0; }
  const int total1 = 131072;               // Wt2s elements
  const int total2 = 65536;                // WtOuts elements
  for (int i = gid; i < total1 + total2; i += stride){
    if (i < total1){
      int tile = i >> 14, E = i & 16383;
      int ph = tile >> 2, by = tile & 3;
      int col = E >> 7, remE = E & 127;
      int unit = (remE >> 3) ^ (col & 7);
      int k = unit * 8 + (remE & 7);
      int c = by * 128 + col;
      float v = ph ? Wres[k * 512 + c] : Wfc[k * 512 + c];
      Wt2s[i] = f2b(v);
    } else {
      int j = i - total1;
      int ph = j >> 14, E = j & 16383;
      int col = E >> 7, remE = E & 127;
      int unit = (remE >> 3) ^ (col & 7);
      int k = unit * 8 + (remE & 7);
      WtOuts[j] = f2b(Wout[(ph * 128 + k) * 128 + col]);
    }
  }
}

// ---- FUSED: dst histogram (blocks 0..1874) + el/er + featb (blocks 1875+) ----
__global__ __launch_bounds__(256) void k_elhist(const float* __restrict__ feat,
                                                const float* __restrict__ P,
                                                const int* __restrict__ dst,
                                                int* __restrict__ counts,
                                                float* __restrict__ el, float* __restrict__ er,
                                                unsigned short* __restrict__ featb){
  __shared__ float sF[32 * 132];
  __shared__ float sP[1024];
  int bx = blockIdx.x;
  if (bx < 1875){
    int e = bx * 256 + threadIdx.x;
    if (e < E_) atomicAdd(&counts[dst[e]], 1);
    return;
  }
  int t = threadIdx.x;
  int n0 = (bx - 1875) * 32;
  *reinterpret_cast<f32x4*>(&sP[t * 4]) = *reinterpret_cast<const f32x4*>(P + t * 4);
#pragma unroll
  for (int i = 0; i < 4; i++){
    int c = t + i * 256;
    int r = c >> 5, cw = (c & 31) * 4;
    int gn = n0 + r;
    f32x4 v = {0.f, 0.f, 0.f, 0.f};
    if (gn < N_) v = *reinterpret_cast<const f32x4*>(feat + gn * 128 + cw);
    *reinterpret_cast<f32x4*>(&sF[r * 132 + cw]) = v;
  }
  __syncthreads();
#pragma unroll
  for (int i = 0; i < 8; i++){
    int c = t + i * 256;                 // dword id 0..2047
    int r = c >> 6, cw = (c & 63) * 2;
    int gn = n0 + r;
    if (gn < N_){
      float v0 = sF[r * 132 + cw], v1 = sF[r * 132 + cw + 1];
      unsigned int pv = (unsigned int)f2b(v0) | ((unsigned int)f2b(v1) << 16);
      *reinterpret_cast<unsigned int*>(featb + gn * 128 + cw) = pv;
    }
  }
  int node = t >> 3, q = t & 7;
  int gn = n0 + node;
  const float* fr = &sF[node * 132];
  float s = 0.f;
#pragma unroll 2
  for (int k = 0; k < 128; k += 4){
    f32x4 fv = *reinterpret_cast<const f32x4*>(fr + k);
#pragma unroll
    for (int j = 0; j < 4; j++) s += fv[j] * sP[(k + j) * 8 + q];
  }
  if (gn < N_){
    if (q < 4) el[gn * 4 + q] = s;
    else       er[gn * 4 + (q - 4)] = s;
  }
}

// ---- exclusive scan -> offs[0..N_], int4-vectorized loads ----
__global__ __launch_bounds__(1024) void k_scan(const int* __restrict__ counts,
                                               int* __restrict__ offs){
  __shared__ int wsum[16];
  int t = threadIdx.x;
  int lane = t & 63, w = t >> 6;
  int base = t * 32;
  int vals[32];
  int s = 0;
  bool inb = (base < N_);
#pragma unroll
  for (int jj = 0; jj < 8; jj++){
    i32x4 cv = {0, 0, 0, 0};
    if (inb) cv = *reinterpret_cast<const i32x4*>(counts + base + jj * 4);
#pragma unroll
    for (int m = 0; m < 4; m++){
      int idx = base + jj * 4 + m;
      int v = (idx < N_) ? cv[m] : 0;
      vals[jj * 4 + m] = s;
      s += v;
    }
  }
  int x = s;
  for (int o = 1; o < 64; o <<= 1){
    int y = __shfl_up(x, o);
    if (lane >= o) x += y;
  }
  if (lane == 63) wsum[w] = x;
  __syncthreads();
  if (t < 16){
    int y = wsum[t];
    for (int o = 1; o < 16; o <<= 1){
      int z = __shfl_up(y, o, 16);
      if (t >= o) y += z;
    }
    wsum[t] = y;
  }
  __syncthreads();
  int wbase = (w > 0) ? wsum[w - 1] : 0;
  int ex = wbase + x - s;
#pragma unroll
  for (int j = 0; j < 32; j++){
    int idx = base + j;
    if (idx <= N_) offs[idx] = ex + vals[j];
  }
}

// ---- per-edge unnormalized softmax weight + CSR scatter ----
__global__ void k_edge(const int* __restrict__ src, const int* __restrict__ dst,
                       const float* __restrict__ el, const float* __restrict__ er,
                       float* __restrict__ ws_s, int* __restrict__ src_s,
                       const int* __restrict__ offs, int* __restrict__ cursor){
  int e = blockIdx.x * 256 + threadIdx.x;
  if (e >= E_) return;
  int s = src[e], d = dst[e];
  f32x4 a = *reinterpret_cast<const f32x4*>(el + s * 4);
  f32x4 b = *reinterpret_cast<const f32x4*>(er + d * 4);
  f32x4 v;
#pragma unroll
  for (int i = 0; i < 4; i++){
    float x = a[i] + b[i];
    x = x > 0.f ? x : 0.2f * x;
    v[i] = __expf(x);
  }
  int p = atomicAdd(&cursor[d], 1);
  int pos = offs[d] + p;
  *reinterpret_cast<f32x4*>(ws_s + pos * 4) = v;
  src_s[pos] = s;
}

// ---- feat-row aggregation: 2 waves/node (edge-split) -> F_agg bf16 ----
// grid 15000 x 256thr: wave (w>>1) owns node, (w&1) owns edge half.
// Partials (acc2 + wsum) combined via LDS; even waves normalize + write.
__global__ __launch_bounds__(256) void k_aggrf(const int* __restrict__ offs,
                                               const int* __restrict__ src_s,
                                               const float* __restrict__ ws_s,
                                               const unsigned short* __restrict__ featb,
                                               unsigned short* __restrict__ fagg){
  __shared__ float red[4][64][8];
  __shared__ float wsr[4][4];
  int wave = threadIdx.x >> 6, lane = threadIdx.x & 63;
  int n = blockIdx.x * 2 + (wave >> 1);      // always < N_ (grid exact)
  int half = wave & 1;
  int off0 = __builtin_amdgcn_readfirstlane(offs[n]);
  int g    = __builtin_amdgcn_readfirstlane(offs[n + 1]) - off0;
  int e0 = half ? (g >> 1) : 0;
  int e1 = half ? g : (g >> 1);
  int c0 = lane * 2;
  f32x2 acc2[4] = {};
  f32x4 wsum = {0.f, 0.f, 0.f, 0.f};

  auto FMA1 = [&](const f32x4& wv, unsigned int pv){
    wsum += wv;
    f32x2 lh; lh[0] = blo(pv); lh[1] = bhi(pv);
#pragma unroll
    for (int h = 0; h < 4; h++) acc2[h] += lh * wv[h];
  };

  int i = e0;
  while (i < e1){
    int blk = e1 - i; if (blk > 64) blk = 64;
    int idx = i + lane;
    int ssrc = (idx < e1) ? src_s[off0 + idx] : 0;
    int nfull = blk >> 3;
    if (nfull){
      int sa[8]; unsigned int pa[8]; f32x4 wa[8];
#pragma unroll
      for (int u = 0; u < 8; u++) sa[u] = __shfl(ssrc, u);
#pragma unroll
      for (int u = 0; u < 8; u++) pa[u] = *reinterpret_cast<const unsigned int*>(featb + sa[u] * 128 + c0);
#pragma unroll
      for (int u = 0; u < 8; u++) wa[u] = *reinterpret_cast<const f32x4*>(ws_s + (off0 + i + u) * 4);
      for (int c = 1; c < nfull; c++){
        int sb[8]; unsigned int pb[8]; f32x4 wb[8];
#pragma unroll
        for (int u = 0; u < 8; u++) sb[u] = __shfl(ssrc, c * 8 + u);
#pragma unroll
        for (int u = 0; u < 8; u++) pb[u] = *reinterpret_cast<const unsigned int*>(featb + sb[u] * 128 + c0);
#pragma unroll
        for (int u = 0; u < 8; u++) wb[u] = *reinterpret_cast<const f32x4*>(ws_s + (off0 + i + c * 8 + u) * 4);
#pragma unroll
        for (int u = 0; u < 8; u++) FMA1(wa[u], pa[u]);
#pragma unroll
        for (int u = 0; u < 8; u++){ pa[u] = pb[u]; wa[u] = wb[u]; }
      }
#pragma unroll
      for (int u = 0; u < 8; u++) FMA1(wa[u], pa[u]);
    }
    for (int j = nfull * 8; j < blk; j++){
      int s = __shfl(ssrc, j);
      unsigned int pv = *reinterpret_cast<const unsigned int*>(featb + s * 128 + c0);
      f32x4 wv = *reinterpret_cast<const f32x4*>(ws_s + (off0 + i + j) * 4);
      FMA1(wv, pv);
    }
    i += blk;
  }

  // cross-wave combine (pairs)
  f32x4 lo = {acc2[0][0], acc2[0][1], acc2[1][0], acc2[1][1]};
  f32x4 hi = {acc2[2][0], acc2[2][1], acc2[3][0], acc2[3][1]};
  *reinterpret_cast<f32x4*>(&red[wave][lane][0]) = lo;
  *reinterpret_cast<f32x4*>(&red[wave][lane][4]) = hi;
  if (lane == 0) *reinterpret_cast<f32x4*>(&wsr[wave][0]) = wsum;
  __syncthreads();
  if (half == 0){
    f32x4 pa = *reinterpret_cast<const f32x4*>(&red[wave + 1][lane][0]);
    f32x4 pb = *reinterpret_cast<const f32x4*>(&red[wave + 1][lane][4]);
    acc2[0][0] += pa[0]; acc2[0][1] += pa[1];
    acc2[1][0] += pa[2]; acc2[1][1] += pa[3];
    acc2[2][0] += pb[0]; acc2[2][1] += pb[1];
    acc2[3][0] += pb[2]; acc2[3][1] += pb[3];
    wsum += *reinterpret_cast<const f32x4*>(&wsr[wave + 1][0]);
    f32x4 rd;
#pragma unroll
    for (int h = 0; h < 4; h++) rd[h] = (wsum[h] > 0.f) ? 1.0f / wsum[h] : 0.f;
#pragma unroll
    for (int h = 0; h < 4; h++){
      unsigned int ov = (unsigned int)f2b(acc2[h][0] * rd[h]) |
                        ((unsigned int)f2b(acc2[h][1] * rd[h]) << 16);
      *reinterpret_cast<unsigned int*>(fagg + n * 512 + h * 128 + c0) = ov;
    }
  }
}

// ---- combined GEMM: rst = F_agg @ Wfc + feat @ Wres + bias -> comb bf16 ----
__global__ __launch_bounds__(512) void k_gemmC(const unsigned short* __restrict__ fagg,
                                               const unsigned short* __restrict__ featb,
                                               const unsigned short* __restrict__ Wt2s,
                                               const float* __restrict__ bias,
                                               unsigned short* __restrict__ comb){
  __shared__ unsigned short wsl[128 * 128];   // 32KB
  char* wb = (char*)wsl;
  int tid = threadIdx.x;
  int wave = tid >> 6, lane = tid & 63;
  int lrow = lane & 15, quad = lane >> 4;
  int rowbase = blockIdx.x * 128 + wave * 16;
  int colbase = blockIdx.y * 128;             // by = head index (0..3)
  int arow = rowbase + lrow; if (arow > N_ - 1) arow = N_ - 1;
  const unsigned short* aF = fagg + arow * 512 + colbase;   // head slice
  const unsigned short* aX = featb + arow * 128;
  f32x4 acc[8] = {};
  for (int phase = 0; phase < 2; phase++){
    __syncthreads();
    {
      const unsigned short* gt = Wt2s + (((phase << 2) | (int)blockIdx.y) << 14);
#pragma unroll
      for (int i = 0; i < 4; i++){
        int off = ((i << 3) | wave) << 9;   // 1KB chunks
        gl_lds16(gt + off + (lane << 3), wsl + off);
      }
    }
    __syncthreads();
#pragma unroll
    for (int kk = 0; kk < 4; kk++){
      Frag a;
      a.q = (phase == 0)
          ? *reinterpret_cast<const u32x4*>(aF + kk * 32 + quad * 8)
          : *reinterpret_cast<const u32x4*>(aX + kk * 32 + quad * 8);
#pragma unroll
      for (int s = 0; s < 8; s++){
        int r = s * 16 + lrow;
        int byte = (r * 256 + kk * 64 + quad * 16) ^ ((r & 7) << 4);
        Frag b; b.q = *reinterpret_cast<const u32x4*>(wb + byte);
        acc[s] = __builtin_amdgcn_mfma_f32_16x16x32_bf16(b.v, a.v, acc[s], 0, 0, 0);
      }
    }
  }
  int gr = rowbase + lrow;
  if (gr < N_){
    unsigned short* crow = comb + gr * 512 + colbase;
#pragma unroll
    for (int s = 0; s < 8; s++){
      f32x4 bb = *reinterpret_cast<const f32x4*>(bias + colbase + s * 16 + quad * 4);
      u32x2 ov;
#pragma unroll
      for (int d = 0; d < 2; d++){
        float v0 = acc[s][2 * d]     + bb[2 * d];
        float v1 = acc[s][2 * d + 1] + bb[2 * d + 1];
        ov[d] = (unsigned int)f2b(v0) | ((unsigned int)f2b(v1) << 16);
      }
      *reinterpret_cast<u32x2*>(crow + s * 16 + quad * 4) = ov;
    }
  }
}

// ---- BN stats: 512 blocks (rows=59), wave partials + LDS block-reduce ----
__global__ __launch_bounds__(256) void k_stats(const unsigned short* __restrict__ comb,
                                               float* __restrict__ psum,
                                               float* __restrict__ psq){
  __shared__ float lsum[4][512];
  __shared__ float lsq[4][512];
  int t = threadIdx.x, lane = t & 63, rg = t >> 6;
  int c0 = lane * 8;
  const int rows = 59;
  int r0 = blockIdx.x * rows;
  int r1 = r0 + rows; if (r1 > N_) r1 = N_;
  float s[8] = {}, q[8] = {};
  for (int r = r0 + rg; r < r1; r += 4){
    u32x4 pv = *reinterpret_cast<const u32x4*>(comb + r * 512 + c0);
#pragma unroll
    for (int d = 0; d < 4; d++){
      float v0 = blo(pv[d]);
      float v1 = bhi(pv[d]);
      s[2*d]   += v0; q[2*d]   += v0 * v0;
      s[2*d+1] += v1; q[2*d+1] += v1 * v1;
    }
  }
#pragma unroll
  for (int d = 0; d < 8; d++){ lsum[rg][c0 + d] = s[d]; lsq[rg][c0 + d] = q[d]; }
  __syncthreads();
#pragma unroll
  for (int half = 0; half < 2; half++){
    int ch = t + half * 256;
    float a = lsum[0][ch] + lsum[1][ch] + lsum[2][ch] + lsum[3][ch];
    float b = lsq[0][ch] + lsq[1][ch] + lsq[2][ch] + lsq[3][ch];
    psum[blockIdx.x * 512 + ch] = a;
    psq[blockIdx.x * 512 + ch] = b;
  }
}

// ---- finalize BN: 4 blocks x 128 ch, reduce 512 block-partials ----
__global__ __launch_bounds__(128) void k_bnfin(const float* __restrict__ psum,
                                               const float* __restrict__ psq,
                                               const float* __restrict__ gamma,
                                               const float* __restrict__ beta,
                                               float* __restrict__ scale,
                                               float* __restrict__ shift){
  int ch = blockIdx.x * 128 + threadIdx.x;
  float s0 = 0.f, s1 = 0.f, s2 = 0.f, s3 = 0.f;
  float q0 = 0.f, q1 = 0.f, q2 = 0.f, q3 = 0.f;
  for (int b = 0; b < 512; b += 4){
    s0 += psum[(b    ) * 512 + ch];
    s1 += psum[(b + 1) * 512 + ch];
    s2 += psum[(b + 2) * 512 + ch];
    s3 += psum[(b + 3) * 512 + ch];
    q0 += psq[(b    ) * 512 + ch];
    q1 += psq[(b + 1) * 512 + ch];
    q2 += psq[(b + 2) * 512 + ch];
    q3 += psq[(b + 3) * 512 + ch];
  }
  float sum = (s0 + s1) + (s2 + s3);
  float sq  = (q0 + q1) + (q2 + q3);
  float mu  = sum / (float)N_;
  float var = sq / (float)N_ - mu * mu;
  float inv = rsqrtf(var + 1e-5f);
  float sc  = gamma[ch] * inv;
  scale[ch] = sc;
  shift[ch] = beta[ch] - mu * sc;
}

// ---- GEMM2: out = relu(BN(comb)) @ Wout + bout, fp32 out ----
__global__ __launch_bounds__(256) void k_gemm2(const unsigned short* __restrict__ comb,
                                               const unsigned short* __restrict__ WtOuts,
                                               const float* __restrict__ scale,
                                               const float* __restrict__ shift,
                                               const float* __restrict__ bout,
                                               float* __restrict__ out){
  __shared__ float sc[512], sh[512];
  __shared__ unsigned short wsl[128 * 128];   // 32KB
  char* wb = (char*)wsl;
  int t = threadIdx.x;
  for (int i = t; i < 512; i += 256){ sc[i] = scale[i]; sh[i] = shift[i]; }
  int wave = t >> 6, lane = t & 63, lrow = lane & 15, quad = lane >> 4;
  int rowbase = blockIdx.x * 64 + wave * 16;
  int rr = rowbase + lrow; if (rr > N_ - 1) rr = N_ - 1;
  const unsigned short* arow = comb + rr * 512;
  f32x4 acc[8] = {};
  for (int phase = 0; phase < 4; phase++){
    __syncthreads();
    {
      const unsigned short* gt = WtOuts + (phase << 14);
#pragma unroll
      for (int i = 0; i < 8; i++){
        int off = ((i << 2) | wave) << 9;
        gl_lds16(gt + off + (lane << 3), wsl + off);
      }
    }
    __syncthreads();
#pragma unroll
    for (int kk = 0; kk < 4; kk++){
      int base = phase * 128 + kk * 32 + quad * 8;
      Frag a; a.q = *reinterpret_cast<const u32x4*>(arow + base);
#pragma unroll
      for (int i2 = 0; i2 < 8; i2++){
        float x = b2f(a.us[i2]);
        x = fmaf(x, sc[base + i2], sh[base + i2]);
        a.us[i2] = f2b(fmaxf(x, 0.0f));
      }
#pragma unroll
      for (int s = 0; s < 8; s++){
        int r = s * 16 + lrow;
        int byte = (r * 256 + kk * 64 + quad * 16) ^ ((r & 7) << 4);
        Frag b; b.q = *reinterpret_cast<const u32x4*>(wb + byte);
        acc[s] = __builtin_amdgcn_mfma_f32_16x16x32_bf16(b.v, a.v, acc[s], 0, 0, 0);
      }
    }
  }
  int gr = rowbase + lrow;
  if (gr < N_){
    float* orow = out + gr * 128;
#pragma unroll
    for (int s = 0; s < 8; s++){
      int cb = s * 16 + quad * 4;
      f32x4 bb = *reinterpret_cast<const f32x4*>(bout + cb);
      f32x4 ov;
#pragma unroll
      for (int j = 0; j < 4; j++) ov[j] = acc[s][j] + bb[j];
      *reinterpret_cast<f32x4*>(orow + cb) = ov;
    }
  }
}

extern "C" void kernel_launch(void* const* d_in, const int* in_sizes, int n_in,
                              void* d_out, int out_size, void* d_ws, size_t ws_size,
                              hipStream_t stream){
  const float* feat  = (const float*)d_in[0];
  const int*   src   = (const int*)d_in[1];
  const int*   dst   = (const int*)d_in[2];
  const float* Wfc   = (const float*)d_in[3];
  const float* al    = (const float*)d_in[4];
  const float* ar    = (const float*)d_in[5];
  const float* Wres  = (const float*)d_in[6];
  const float* bias  = (const float*)d_in[7];
  const float* gamma = (const float*)d_in[8];
  const float* beta  = (const float*)d_in[9];
  const float* Wout  = (const float*)d_in[10];
  const float* bout  = (const float*)d_in[11];
  float* out = (float*)d_out;

  char* ws = (char*)d_ws;
  unsigned short* comb  = (unsigned short*)(ws + 0);           // 30,720,000
  unsigned short* fagg  = (unsigned short*)(ws + 30720000);    // 30,720,000
  unsigned short* Wt2s  = (unsigned short*)(ws + 61440000);    //    262,144
  unsigned short* WtOuts= (unsigned short*)(ws + 61702144);    //    131,072
  float*          el    = (float*)(ws + 61833216);             //    480,000
  float*          er    = (float*)(ws + 62313216);             //    480,000
  float*          ws_s  = (float*)(ws + 62793216);             //  7,680,000
  int*            offs  = (int*)(ws + 70473216);               //    120,064
  int*            counts= (int*)(ws + 70593280);               //    120,000
  int*            cursor= (int*)(ws + 70713280);               //    120,000
  int*            src_s = (int*)(ws + 70833280);               //  1,920,000
  float*          Pbuf  = (float*)(ws + 72753280);             //      8,192 (P)
  float*          scale = (float*)(ws + 73801856);             //      2,048
  float*          shift = (float*)(ws + 73803904);             //      2,048
  unsigned short* featb = (unsigned short*)(ws + 73805952);    //  7,680,000
  // stats partials overlay the dead ws_s region (dead after k_aggrf):
  float*          psumS = (float*)(ws + 62793216);             //  1,048,576
  float*          psqS  = (float*)(ws + 63841792);             //  1,048,576

  k_initconv<<<260, 256, 0, stream>>>(Wfc, Wres, Wout, al, ar, Wt2s, WtOuts, Pbuf,
                                      counts, cursor);
  k_elhist<<<1875 + (N_ + 31) / 32, 256, 0, stream>>>(feat, Pbuf, dst, counts,
                                                      el, er, featb);
  k_scan<<<1, 1024, 0, stream>>>(counts, offs);
  k_edge<<<(E_ + 255) / 256, 256, 0, stream>>>(src, dst, el, er, ws_s, src_s, offs, cursor);
  k_aggrf<<<N_ / 2, 256, 0, stream>>>(offs, src_s, ws_s, featb, fagg);
  dim3 gC((N_ + 127) / 128, 4);
  k_gemmC<<<gC, 512, 0, stream>>>(fagg, featb, Wt2s, bias, comb);
  k_stats<<<512, 256, 0, stream>>>(comb, psumS, psqS);
  k_bnfin<<<4, 128, 0, stream>>>(psumS, psqS, gamma, beta, scale, shift);
  k_gemm2<<<(N_ + 63) / 64, 256, 0, stream>>>(comb, WtOuts, scale, shift, bout, out);
}

// Round 9
// 264.335 us; speedup vs baseline: 1.0788x; 1.0788x over previous
//
#include <hip/hip_runtime.h>

#define N_  30000
#define E_  480000

typedef short short8 __attribute__((ext_vector_type(8)));
typedef float f32x4  __attribute__((ext_vector_type(4)));
typedef float f32x2  __attribute__((ext_vector_type(2)));
typedef unsigned int u32x4 __attribute__((ext_vector_type(4)));
typedef unsigned int u32x2 __attribute__((ext_vector_type(2)));
typedef int i32x4 __attribute__((ext_vector_type(4)));
union Frag { u32x4 q; short8 v; unsigned short us[8]; };

__device__ __forceinline__ float b2f(unsigned short u){
  union { unsigned int i; float f; } v; v.i = ((unsigned int)u) << 16; return v.f;
}
__device__ __forceinline__ float blo(unsigned int u){
  union { unsigned int i; float f; } v; v.i = u << 16; return v.f;
}
__device__ __forceinline__ float bhi(unsigned int u){
  union { unsigned int i; float f; } v; v.i = u & 0xffff0000u; return v.f;
}
__device__ __forceinline__ unsigned short f2b(float f){
  union { float f; unsigned int u; } v; v.f = f;
  unsigned int u = v.u;
  return (unsigned short)((u + 0x7fffu + ((u >> 16) & 1u)) >> 16);
}
// direct global->LDS 16B copy (dest = wave-uniform base + lane*16)
__device__ __forceinline__ void gl_lds16(const unsigned short* g, unsigned short* l){
  __builtin_amdgcn_global_load_lds(
      (const __attribute__((address_space(1))) unsigned int*)g,
      (__attribute__((address_space(3))) unsigned int*)l, 16, 0, 0);
}

// ---- init scratch + PRE-SWIZZLED weight LDS-images + P fold ----
__global__ void k_initconv(const float* __restrict__ Wfc, const float* __restrict__ Wres,
                           const float* __restrict__ Wout,
                           const float* __restrict__ al, const float* __restrict__ ar,
                           unsigned short* __restrict__ Wt2s, unsigned short* __restrict__ WtOuts,
                           float* __restrict__ P,
                           int* __restrict__ counts, int* __restrict__ cursor){
  int bx = blockIdx.x;
  if (bx >= 256){
    int idx = (bx - 256) * 256 + threadIdx.x;   // 0..1023
    if (idx < 1024){
      int k = idx >> 3, q = idx & 7;
      int h = q & 3;
      const float* a = (q < 4) ? al : ar;
      const float* wr = Wfc + k * 512 + h * 128;
      const float* av = a + h * 128;
      float s = 0.f;
#pragma unroll 4
      for (int d = 0; d < 128; d++) s += wr[d] * av[d];
      P[k * 8 + q] = s;
    }
    return;
  }
  int gid = bx * 256 + threadIdx.x;
  const int stride = 256 * 256;
  if (gid < N_){ counts[gid] = 0; cursor[gid] = 0; }
  const int total1 = 131072;               // Wt2s elements
  const int total2 = 65536;                // WtOuts elements
  for (int i = gid; i < total1 + total2; i += stride){
    if (i < total1){
      int tile = i >> 14, E = i & 16383;
      int ph = tile >> 2, by = tile & 3;
      int col = E >> 7, remE = E & 127;
      int unit = (remE >> 3) ^ (col & 7);
      int k = unit * 8 + (remE & 7);
      int c = by * 128 + col;
      float v = ph ? Wres[k * 512 + c] : Wfc[k * 512 + c];
      Wt2s[i] = f2b(v);
    } else {
      int j = i - total1;
      int ph = j >> 14, E = j & 16383;
      int col = E >> 7, remE = E & 127;
      int unit = (remE >> 3) ^ (col & 7);
      int k = unit * 8 + (remE & 7);
      WtOuts[j] = f2b(Wout[(ph * 128 + k) * 128 + col]);
    }
  }
}

// ---- FUSED: dst histogram (blocks 0..1874) + el/er + featb (blocks 1875+) ----
__global__ __launch_bounds__(256) void k_elhist(const float* __restrict__ feat,
                                                const float* __restrict__ P,
                                                const int* __restrict__ dst,
                                                int* __restrict__ counts,
                                                float* __restrict__ el, float* __restrict__ er,
                                                unsigned short* __restrict__ featb){
  __shared__ float sF[32 * 132];
  __shared__ float sP[1024];
  int bx = blockIdx.x;
  if (bx < 1875){
    int e = bx * 256 + threadIdx.x;
    if (e < E_) atomicAdd(&counts[dst[e]], 1);
    return;
  }
  int t = threadIdx.x;
  int n0 = (bx - 1875) * 32;
  *reinterpret_cast<f32x4*>(&sP[t * 4]) = *reinterpret_cast<const f32x4*>(P + t * 4);
#pragma unroll
  for (int i = 0; i < 4; i++){
    int c = t + i * 256;
    int r = c >> 5, cw = (c & 31) * 4;
    int gn = n0 + r;
    f32x4 v = {0.f, 0.f, 0.f, 0.f};
    if (gn < N_) v = *reinterpret_cast<const f32x4*>(feat + gn * 128 + cw);
    *reinterpret_cast<f32x4*>(&sF[r * 132 + cw]) = v;
  }
  __syncthreads();
#pragma unroll
  for (int i = 0; i < 8; i++){
    int c = t + i * 256;                 // dword id 0..2047
    int r = c >> 6, cw = (c & 63) * 2;
    int gn = n0 + r;
    if (gn < N_){
      float v0 = sF[r * 132 + cw], v1 = sF[r * 132 + cw + 1];
      unsigned int pv = (unsigned int)f2b(v0) | ((unsigned int)f2b(v1) << 16);
      *reinterpret_cast<unsigned int*>(featb + gn * 128 + cw) = pv;
    }
  }
  int node = t >> 3, q = t & 7;
  int gn = n0 + node;
  const float* fr = &sF[node * 132];
  float s = 0.f;
#pragma unroll 2
  for (int k = 0; k < 128; k += 4){
    f32x4 fv = *reinterpret_cast<const f32x4*>(fr + k);
#pragma unroll
    for (int j = 0; j < 4; j++) s += fv[j] * sP[(k + j) * 8 + q];
  }
  if (gn < N_){
    if (q < 4) el[gn * 4 + q] = s;
    else       er[gn * 4 + (q - 4)] = s;
  }
}

// ---- exclusive scan -> offs[0..N_], int4-vectorized loads ----
__global__ __launch_bounds__(1024) void k_scan(const int* __restrict__ counts,
                                               int* __restrict__ offs){
  __shared__ int wsum[16];
  int t = threadIdx.x;
  int lane = t & 63, w = t >> 6;
  int base = t * 32;
  int vals[32];
  int s = 0;
  bool inb = (base < N_);
#pragma unroll
  for (int jj = 0; jj < 8; jj++){
    i32x4 cv = {0, 0, 0, 0};
    if (inb) cv = *reinterpret_cast<const i32x4*>(counts + base + jj * 4);
#pragma unroll
    for (int m = 0; m < 4; m++){
      int idx = base + jj * 4 + m;
      int v = (idx < N_) ? cv[m] : 0;
      vals[jj * 4 + m] = s;
      s += v;
    }
  }
  int x = s;
  for (int o = 1; o < 64; o <<= 1){
    int y = __shfl_up(x, o);
    if (lane >= o) x += y;
  }
  if (lane == 63) wsum[w] = x;
  __syncthreads();
  if (t < 16){
    int y = wsum[t];
    for (int o = 1; o < 16; o <<= 1){
      int z = __shfl_up(y, o, 16);
      if (t >= o) y += z;
    }
    wsum[t] = y;
  }
  __syncthreads();
  int wbase = (w > 0) ? wsum[w - 1] : 0;
  int ex = wbase + x - s;
#pragma unroll
  for (int j = 0; j < 32; j++){
    int idx = base + j;
    if (idx <= N_) offs[idx] = ex + vals[j];
  }
}

// ---- per-edge unnormalized softmax weight + CSR scatter ----
__global__ void k_edge(const int* __restrict__ src, const int* __restrict__ dst,
                       const float* __restrict__ el, const float* __restrict__ er,
                       float* __restrict__ ws_s, int* __restrict__ src_s,
                       const int* __restrict__ offs, int* __restrict__ cursor){
  int e = blockIdx.x * 256 + threadIdx.x;
  if (e >= E_) return;
  int s = src[e], d = dst[e];
  f32x4 a = *reinterpret_cast<const f32x4*>(el + s * 4);
  f32x4 b = *reinterpret_cast<const f32x4*>(er + d * 4);
  f32x4 v;
#pragma unroll
  for (int i = 0; i < 4; i++){
    float x = a[i] + b[i];
    x = x > 0.f ? x : 0.2f * x;
    v[i] = __expf(x);
  }
  int p = atomicAdd(&cursor[d], 1);
  int pos = offs[d] + p;
  *reinterpret_cast<f32x4*>(ws_s + pos * 4) = v;
  src_s[pos] = s;
}

// ---- feat-row aggregation, prepass-free: F_agg[n][h][128] bf16 ----
// REVERTED to 1 wave/node (r8's 2-wave split: 16-way LDS conflicts + broken
// pipeline at deg/2=8 edges -> 2x regression). 8-deep software pipeline.
__global__ __launch_bounds__(256) void k_aggrf(const int* __restrict__ offs,
                                               const int* __restrict__ src_s,
                                               const float* __restrict__ ws_s,
                                               const unsigned short* __restrict__ featb,
                                               unsigned short* __restrict__ fagg){
  int wave = threadIdx.x >> 6, lane = threadIdx.x & 63;
  int n = blockIdx.x * 4 + wave;
  if (n >= N_) return;
  int off0 = __builtin_amdgcn_readfirstlane(offs[n]);
  int g    = __builtin_amdgcn_readfirstlane(offs[n + 1]) - off0;
  int c0 = lane * 2;
  f32x2 acc2[4] = {};
  f32x4 wsum = {0.f, 0.f, 0.f, 0.f};

  auto FMA1 = [&](const f32x4& wv, unsigned int pv){
    wsum += wv;
    f32x2 lh; lh[0] = blo(pv); lh[1] = bhi(pv);
#pragma unroll
    for (int h = 0; h < 4; h++) acc2[h] += lh * wv[h];
  };

  int i = 0;
  while (i < g){
    int blk = g - i; if (blk > 64) blk = 64;
    int idx = i + lane;
    int ssrc = (idx < g) ? src_s[off0 + idx] : 0;
    int nfull = blk >> 3;
    if (nfull){
      int sa[8]; unsigned int pa[8]; f32x4 wa[8];
#pragma unroll
      for (int u = 0; u < 8; u++) sa[u] = __shfl(ssrc, u);
#pragma unroll
      for (int u = 0; u < 8; u++) pa[u] = *reinterpret_cast<const unsigned int*>(featb + sa[u] * 128 + c0);
#pragma unroll
      for (int u = 0; u < 8; u++) wa[u] = *reinterpret_cast<const f32x4*>(ws_s + (off0 + i + u) * 4);
      for (int c = 1; c < nfull; c++){
        int sb[8]; unsigned int pb[8]; f32x4 wb[8];
#pragma unroll
        for (int u = 0; u < 8; u++) sb[u] = __shfl(ssrc, c * 8 + u);
#pragma unroll
        for (int u = 0; u < 8; u++) pb[u] = *reinterpret_cast<const unsigned int*>(featb + sb[u] * 128 + c0);
#pragma unroll
        for (int u = 0; u < 8; u++) wb[u] = *reinterpret_cast<const f32x4*>(ws_s + (off0 + i + c * 8 + u) * 4);
#pragma unroll
        for (int u = 0; u < 8; u++) FMA1(wa[u], pa[u]);
#pragma unroll
        for (int u = 0; u < 8; u++){ pa[u] = pb[u]; wa[u] = wb[u]; }
      }
#pragma unroll
      for (int u = 0; u < 8; u++) FMA1(wa[u], pa[u]);
    }
    for (int j = nfull * 8; j < blk; j++){
      int s = __shfl(ssrc, j);
      unsigned int pv = *reinterpret_cast<const unsigned int*>(featb + s * 128 + c0);
      f32x4 wv = *reinterpret_cast<const f32x4*>(ws_s + (off0 + i + j) * 4);
      FMA1(wv, pv);
    }
    i += blk;
  }

  f32x4 rd;
#pragma unroll
  for (int h = 0; h < 4; h++) rd[h] = (wsum[h] > 0.f) ? 1.0f / wsum[h] : 0.f;
#pragma unroll
  for (int h = 0; h < 4; h++){
    unsigned int ov = (unsigned int)f2b(acc2[h][0] * rd[h]) |
                      ((unsigned int)f2b(acc2[h][1] * rd[h]) << 16);
    *reinterpret_cast<unsigned int*>(fagg + n * 512 + h * 128 + c0) = ov;
  }
}

// ---- combined GEMM: rst = F_agg @ Wfc + feat @ Wres + bias -> comb bf16 ----
__global__ __launch_bounds__(512) void k_gemmC(const unsigned short* __restrict__ fagg,
                                               const unsigned short* __restrict__ featb,
                                               const unsigned short* __restrict__ Wt2s,
                                               const float* __restrict__ bias,
                                               unsigned short* __restrict__ comb){
  __shared__ unsigned short wsl[128 * 128];   // 32KB
  char* wb = (char*)wsl;
  int tid = threadIdx.x;
  int wave = tid >> 6, lane = tid & 63;
  int lrow = lane & 15, quad = lane >> 4;
  int rowbase = blockIdx.x * 128 + wave * 16;
  int colbase = blockIdx.y * 128;             // by = head index (0..3)
  int arow = rowbase + lrow; if (arow > N_ - 1) arow = N_ - 1;
  const unsigned short* aF = fagg + arow * 512 + colbase;   // head slice
  const unsigned short* aX = featb + arow * 128;
  f32x4 acc[8] = {};
  for (int phase = 0; phase < 2; phase++){
    __syncthreads();
    {
      const unsigned short* gt = Wt2s + (((phase << 2) | (int)blockIdx.y) << 14);
#pragma unroll
      for (int i = 0; i < 4; i++){
        int off = ((i << 3) | wave) << 9;   // 1KB chunks
        gl_lds16(gt + off + (lane << 3), wsl + off);
      }
    }
    __syncthreads();
#pragma unroll
    for (int kk = 0; kk < 4; kk++){
      Frag a;
      a.q = (phase == 0)
          ? *reinterpret_cast<const u32x4*>(aF + kk * 32 + quad * 8)
          : *reinterpret_cast<const u32x4*>(aX + kk * 32 + quad * 8);
#pragma unroll
      for (int s = 0; s < 8; s++){
        int r = s * 16 + lrow;
        int byte = (r * 256 + kk * 64 + quad * 16) ^ ((r & 7) << 4);
        Frag b; b.q = *reinterpret_cast<const u32x4*>(wb + byte);
        acc[s] = __builtin_amdgcn_mfma_f32_16x16x32_bf16(b.v, a.v, acc[s], 0, 0, 0);
      }
    }
  }
  int gr = rowbase + lrow;
  if (gr < N_){
    unsigned short* crow = comb + gr * 512 + colbase;
#pragma unroll
    for (int s = 0; s < 8; s++){
      f32x4 bb = *reinterpret_cast<const f32x4*>(bias + colbase + s * 16 + quad * 4);
      u32x2 ov;
#pragma unroll
      for (int d = 0; d < 2; d++){
        float v0 = acc[s][2 * d]     + bb[2 * d];
        float v1 = acc[s][2 * d + 1] + bb[2 * d + 1];
        ov[d] = (unsigned int)f2b(v0) | ((unsigned int)f2b(v1) << 16);
      }
      *reinterpret_cast<u32x2*>(crow + s * 16 + quad * 4) = ov;
    }
  }
}

// ---- BN stats: 512 blocks (rows=59), wave partials + LDS block-reduce ----
__global__ __launch_bounds__(256) void k_stats(const unsigned short* __restrict__ comb,
                                               float* __restrict__ psum,
                                               float* __restrict__ psq){
  __shared__ float lsum[4][512];
  __shared__ float lsq[4][512];
  int t = threadIdx.x, lane = t & 63, rg = t >> 6;
  int c0 = lane * 8;
  const int rows = 59;
  int r0 = blockIdx.x * rows;
  int r1 = r0 + rows; if (r1 > N_) r1 = N_;
  float s[8] = {}, q[8] = {};
  for (int r = r0 + rg; r < r1; r += 4){
    u32x4 pv = *reinterpret_cast<const u32x4*>(comb + r * 512 + c0);
#pragma unroll
    for (int d = 0; d < 4; d++){
      float v0 = blo(pv[d]);
      float v1 = bhi(pv[d]);
      s[2*d]   += v0; q[2*d]   += v0 * v0;
      s[2*d+1] += v1; q[2*d+1] += v1 * v1;
    }
  }
#pragma unroll
  for (int d = 0; d < 8; d++){ lsum[rg][c0 + d] = s[d]; lsq[rg][c0 + d] = q[d]; }
  __syncthreads();
#pragma unroll
  for (int half = 0; half < 2; half++){
    int ch = t + half * 256;
    float a = lsum[0][ch] + lsum[1][ch] + lsum[2][ch] + lsum[3][ch];
    float b = lsq[0][ch] + lsq[1][ch] + lsq[2][ch] + lsq[3][ch];
    psum[blockIdx.x * 512 + ch] = a;
    psq[blockIdx.x * 512 + ch] = b;
  }
}

// ---- finalize BN: 4 blocks x 128 ch, reduce 512 block-partials ----
__global__ __launch_bounds__(128) void k_bnfin(const float* __restrict__ psum,
                                               const float* __restrict__ psq,
                                               const float* __restrict__ gamma,
                                               const float* __restrict__ beta,
                                               float* __restrict__ scale,
                                               float* __restrict__ shift){
  int ch = blockIdx.x * 128 + threadIdx.x;
  float s0 = 0.f, s1 = 0.f, s2 = 0.f, s3 = 0.f;
  float q0 = 0.f, q1 = 0.f, q2 = 0.f, q3 = 0.f;
  for (int b = 0; b < 512; b += 4){
    s0 += psum[(b    ) * 512 + ch];
    s1 += psum[(b + 1) * 512 + ch];
    s2 += psum[(b + 2) * 512 + ch];
    s3 += psum[(b + 3) * 512 + ch];
    q0 += psq[(b    ) * 512 + ch];
    q1 += psq[(b + 1) * 512 + ch];
    q2 += psq[(b + 2) * 512 + ch];
    q3 += psq[(b + 3) * 512 + ch];
  }
  float sum = (s0 + s1) + (s2 + s3);
  float sq  = (q0 + q1) + (q2 + q3);
  float mu  = sum / (float)N_;
  float var = sq / (float)N_ - mu * mu;
  float inv = rsqrtf(var + 1e-5f);
  float sc  = gamma[ch] * inv;
  scale[ch] = sc;
  shift[ch] = beta[ch] - mu * sc;
}

// ---- GEMM2: out = relu(BN(comb)) @ Wout + bout, fp32 out ----
__global__ __launch_bounds__(256) void k_gemm2(const unsigned short* __restrict__ comb,
                                               const unsigned short* __restrict__ WtOuts,
                                               const float* __restrict__ scale,
                                               const float* __restrict__ shift,
                                               const float* __restrict__ bout,
                                               float* __restrict__ out){
  __shared__ float sc[512], sh[512];
  __shared__ unsigned short wsl[128 * 128];   // 32KB
  char* wb = (char*)wsl;
  int t = threadIdx.x;
  for (int i = t; i < 512; i += 256){ sc[i] = scale[i]; sh[i] = shift[i]; }
  int wave = t >> 6, lane = t & 63, lrow = lane & 15, quad = lane >> 4;
  int rowbase = blockIdx.x * 64 + wave * 16;
  int rr = rowbase + lrow; if (rr > N_ - 1) rr = N_ - 1;
  const unsigned short* arow = comb + rr * 512;
  f32x4 acc[8] = {};
  for (int phase = 0; phase < 4; phase++){
    __syncthreads();
    {
      const unsigned short* gt = WtOuts + (phase << 14);
#pragma unroll
      for (int i = 0; i < 8; i++){
        int off = ((i << 2) | wave) << 9;
        gl_lds16(gt + off + (lane << 3), wsl + off);
      }
    }
    __syncthreads();
#pragma unroll
    for (int kk = 0; kk < 4; kk++){
      int base = phase * 128 + kk * 32 + quad * 8;
      Frag a; a.q = *reinterpret_cast<const u32x4*>(arow + base);
#pragma unroll
      for (int i2 = 0; i2 < 8; i2++){
        float x = b2f(a.us[i2]);
        x = fmaf(x, sc[base + i2], sh[base + i2]);
        a.us[i2] = f2b(fmaxf(x, 0.0f));
      }
#pragma unroll
      for (int s = 0; s < 8; s++){
        int r = s * 16 + lrow;
        int byte = (r * 256 + kk * 64 + quad * 16) ^ ((r & 7) << 4);
        Frag b; b.q = *reinterpret_cast<const u32x4*>(wb + byte);
        acc[s] = __builtin_amdgcn_mfma_f32_16x16x32_bf16(b.v, a.v, acc[s], 0, 0, 0);
      }
    }
  }
  int gr = rowbase + lrow;
  if (gr < N_){
    float* orow = out + gr * 128;
#pragma unroll
    for (int s = 0; s < 8; s++){
      int cb = s * 16 + quad * 4;
      f32x4 bb = *reinterpret_cast<const f32x4*>(bout + cb);
      f32x4 ov;
#pragma unroll
      for (int j = 0; j < 4; j++) ov[j] = acc[s][j] + bb[j];
      *reinterpret_cast<f32x4*>(orow + cb) = ov;
    }
  }
}

extern "C" void kernel_launch(void* const* d_in, const int* in_sizes, int n_in,
                              void* d_out, int out_size, void* d_ws, size_t ws_size,
                              hipStream_t stream){
  const float* feat  = (const float*)d_in[0];
  const int*   src   = (const int*)d_in[1];
  const int*   dst   = (const int*)d_in[2];
  const float* Wfc   = (const float*)d_in[3];
  const float* al    = (const float*)d_in[4];
  const float* ar    = (const float*)d_in[5];
  const float* Wres  = (const float*)d_in[6];
  const float* bias  = (const float*)d_in[7];
  const float* gamma = (const float*)d_in[8];
  const float* beta  = (const float*)d_in[9];
  const float* Wout  = (const float*)d_in[10];
  const float* bout  = (const float*)d_in[11];
  float* out = (float*)d_out;

  char* ws = (char*)d_ws;
  unsigned short* comb  = (unsigned short*)(ws + 0);           // 30,720,000
  unsigned short* fagg  = (unsigned short*)(ws + 30720000);    // 30,720,000
  unsigned short* Wt2s  = (unsigned short*)(ws + 61440000);    //    262,144
  unsigned short* WtOuts= (unsigned short*)(ws + 61702144);    //    131,072
  float*          el    = (float*)(ws + 61833216);             //    480,000
  float*          er    = (float*)(ws + 62313216);             //    480,000
  float*          ws_s  = (float*)(ws + 62793216);             //  7,680,000
  int*            offs  = (int*)(ws + 70473216);               //    120,064
  int*            counts= (int*)(ws + 70593280);               //    120,000
  int*            cursor= (int*)(ws + 70713280);               //    120,000
  int*            src_s = (int*)(ws + 70833280);               //  1,920,000
  float*          Pbuf  = (float*)(ws + 72753280);             //      8,192 (P)
  float*          scale = (float*)(ws + 73801856);             //      2,048
  float*          shift = (float*)(ws + 73803904);             //      2,048
  unsigned short* featb = (unsigned short*)(ws + 73805952);    //  7,680,000
  // stats partials overlay the dead ws_s region (dead after k_aggrf):
  float*          psumS = (float*)(ws + 62793216);             //  1,048,576
  float*          psqS  = (float*)(ws + 63841792);             //  1,048,576

  k_initconv<<<260, 256, 0, stream>>>(Wfc, Wres, Wout, al, ar, Wt2s, WtOuts, Pbuf,
                                      counts, cursor);
  k_elhist<<<1875 + (N_ + 31) / 32, 256, 0, stream>>>(feat, Pbuf, dst, counts,
                                                      el, er, featb);
  k_scan<<<1, 1024, 0, stream>>>(counts, offs);
  k_edge<<<(E_ + 255) / 256, 256, 0, stream>>>(src, dst, el, er, ws_s, src_s, offs, cursor);
  k_aggrf<<<(N_ + 3) / 4, 256, 0, stream>>>(offs, src_s, ws_s, featb, fagg);
  dim3 gC((N_ + 127) / 128, 4);
  k_gemmC<<<gC, 512, 0, stream>>>(fagg, featb, Wt2s, bias, comb);
  k_stats<<<512, 256, 0, stream>>>(comb, psumS, psqS);
  k_bnfin<<<4, 128, 0, stream>>>(psumS, psqS, gamma, beta, scale, shift);
  k_gemm2<<<(N_ + 63) / 64, 256, 0, stream>>>(comb, WtOuts, scale, shift, bout, out);
}

// Round 11
// 263.482 us; speedup vs baseline: 1.0823x; 1.0032x over previous
//
#include <hip/hip_runtime.h>

#define N_  30000
#define E_  480000

typedef short short8 __attribute__((ext_vector_type(8)));
typedef float f32x4  __attribute__((ext_vector_type(4)));
typedef float f32x2  __attribute__((ext_vector_type(2)));
typedef unsigned int u32x4 __attribute__((ext_vector_type(4)));
typedef unsigned int u32x2 __attribute__((ext_vector_type(2)));
typedef int i32x4 __attribute__((ext_vector_type(4)));
union Frag { u32x4 q; short8 v; unsigned short us[8]; };

__device__ __forceinline__ float b2f(unsigned short u){
  union { unsigned int i; float f; } v; v.i = ((unsigned int)u) << 16; return v.f;
}
__device__ __forceinline__ float blo(unsigned int u){
  union { unsigned int i; float f; } v; v.i = u << 16; return v.f;
}
__device__ __forceinline__ float bhi(unsigned int u){
  union { unsigned int i; float f; } v; v.i = u & 0xffff0000u; return v.f;
}
__device__ __forceinline__ unsigned short f2b(float f){
  union { float f; unsigned int u; } v; v.f = f;
  unsigned int u = v.u;
  return (unsigned short)((u + 0x7fffu + ((u >> 16) & 1u)) >> 16);
}
// direct global->LDS 16B copy (dest = wave-uniform base + lane*16)
__device__ __forceinline__ void gl_lds16(const unsigned short* g, unsigned short* l){
  __builtin_amdgcn_global_load_lds(
      (const __attribute__((address_space(1))) unsigned int*)g,
      (__attribute__((address_space(3))) unsigned int*)l, 16, 0, 0);
}

// ---- init scratch + PRE-SWIZZLED weight LDS-images + P fold ----
__global__ void k_initconv(const float* __restrict__ Wfc, const float* __restrict__ Wres,
                           const float* __restrict__ Wout,
                           const float* __restrict__ al, const float* __restrict__ ar,
                           unsigned short* __restrict__ Wt2s, unsigned short* __restrict__ WtOuts,
                           float* __restrict__ P,
                           int* __restrict__ counts, int* __restrict__ cursor){
  int bx = blockIdx.x;
  if (bx >= 256){
    int idx = (bx - 256) * 256 + threadIdx.x;   // 0..1023
    if (idx < 1024){
      int k = idx >> 3, q = idx & 7;
      int h = q & 3;
      const float* a = (q < 4) ? al : ar;
      const float* wr = Wfc + k * 512 + h * 128;
      const float* av = a + h * 128;
      float s = 0.f;
#pragma unroll 4
      for (int d = 0; d < 128; d++) s += wr[d] * av[d];
      P[k * 8 + q] = s;
    }
    return;
  }
  int gid = bx * 256 + threadIdx.x;
  const int stride = 256 * 256;
  if (gid < N_){ counts[gid] = 0; cursor[gid] = 0; }
  const int total1 = 131072;               // Wt2s elements
  const int total2 = 65536;                // WtOuts elements
  for (int i = gid; i < total1 + total2; i += stride){
    if (i < total1){
      int tile = i >> 14, E = i & 16383;
      int ph = tile >> 2, by = tile & 3;
      int col = E >> 7, remE = E & 127;
      int unit = (remE >> 3) ^ (col & 7);
      int k = unit * 8 + (remE & 7);
      int c = by * 128 + col;
      float v = ph ? Wres[k * 512 + c] : Wfc[k * 512 + c];
      Wt2s[i] = f2b(v);
    } else {
      int j = i - total1;
      int ph = j >> 14, E = j & 16383;
      int col = E >> 7, remE = E & 127;
      int unit = (remE >> 3) ^ (col & 7);
      int k = unit * 8 + (remE & 7);
      WtOuts[j] = f2b(Wout[(ph * 128 + k) * 128 + col]);
    }
  }
}

// ---- FUSED: dst histogram (blocks 0..1874) + el/er + featb (blocks 1875+) ----
__global__ __launch_bounds__(256) void k_elhist(const float* __restrict__ feat,
                                                const float* __restrict__ P,
                                                const int* __restrict__ dst,
                                                int* __restrict__ counts,
                                                float* __restrict__ el, float* __restrict__ er,
                                                unsigned short* __restrict__ featb){
  __shared__ float sF[32 * 132];
  __shared__ float sP[1024];
  int bx = blockIdx.x;
  if (bx < 1875){
    int e = bx * 256 + threadIdx.x;
    if (e < E_) atomicAdd(&counts[dst[e]], 1);
    return;
  }
  int t = threadIdx.x;
  int n0 = (bx - 1875) * 32;
  *reinterpret_cast<f32x4*>(&sP[t * 4]) = *reinterpret_cast<const f32x4*>(P + t * 4);
#pragma unroll
  for (int i = 0; i < 4; i++){
    int c = t + i * 256;
    int r = c >> 5, cw = (c & 31) * 4;
    int gn = n0 + r;
    f32x4 v = {0.f, 0.f, 0.f, 0.f};
    if (gn < N_) v = *reinterpret_cast<const f32x4*>(feat + gn * 128 + cw);
    *reinterpret_cast<f32x4*>(&sF[r * 132 + cw]) = v;
  }
  __syncthreads();
#pragma unroll
  for (int i = 0; i < 8; i++){
    int c = t + i * 256;                 // dword id 0..2047
    int r = c >> 6, cw = (c & 63) * 2;
    int gn = n0 + r;
    if (gn < N_){
      float v0 = sF[r * 132 + cw], v1 = sF[r * 132 + cw + 1];
      unsigned int pv = (unsigned int)f2b(v0) | ((unsigned int)f2b(v1) << 16);
      *reinterpret_cast<unsigned int*>(featb + gn * 128 + cw) = pv;
    }
  }
  int node = t >> 3, q = t & 7;
  int gn = n0 + node;
  const float* fr = &sF[node * 132];
  float s = 0.f;
#pragma unroll 2
  for (int k = 0; k < 128; k += 4){
    f32x4 fv = *reinterpret_cast<const f32x4*>(fr + k);
#pragma unroll
    for (int j = 0; j < 4; j++) s += fv[j] * sP[(k + j) * 8 + q];
  }
  if (gn < N_){
    if (q < 4) el[gn * 4 + q] = s;
    else       er[gn * 4 + (q - 4)] = s;
  }
}

// ---- exclusive scan -> offs[0..N_], int4-vectorized loads ----
__global__ __launch_bounds__(1024) void k_scan(const int* __restrict__ counts,
                                               int* __restrict__ offs){
  __shared__ int wsum[16];
  int t = threadIdx.x;
  int lane = t & 63, w = t >> 6;
  int base = t * 32;
  int vals[32];
  int s = 0;
  bool inb = (base < N_);
#pragma unroll
  for (int jj = 0; jj < 8; jj++){
    i32x4 cv = {0, 0, 0, 0};
    if (inb) cv = *reinterpret_cast<const i32x4*>(counts + base + jj * 4);
#pragma unroll
    for (int m = 0; m < 4; m++){
      int idx = base + jj * 4 + m;
      int v = (idx < N_) ? cv[m] : 0;
      vals[jj * 4 + m] = s;
      s += v;
    }
  }
  int x = s;
  for (int o = 1; o < 64; o <<= 1){
    int y = __shfl_up(x, o);
    if (lane >= o) x += y;
  }
  if (lane == 63) wsum[w] = x;
  __syncthreads();
  if (t < 16){
    int y = wsum[t];
    for (int o = 1; o < 16; o <<= 1){
      int z = __shfl_up(y, o, 16);
      if (t >= o) y += z;
    }
    wsum[t] = y;
  }
  __syncthreads();
  int wbase = (w > 0) ? wsum[w - 1] : 0;
  int ex = wbase + x - s;
#pragma unroll
  for (int j = 0; j < 32; j++){
    int idx = base + j;
    if (idx <= N_) offs[idx] = ex + vals[j];
  }
}

// ---- per-edge unnormalized softmax weight + CSR scatter ----
__global__ void k_edge(const int* __restrict__ src, const int* __restrict__ dst,
                       const float* __restrict__ el, const float* __restrict__ er,
                       float* __restrict__ ws_s, int* __restrict__ src_s,
                       const int* __restrict__ offs, int* __restrict__ cursor){
  int e = blockIdx.x * 256 + threadIdx.x;
  if (e >= E_) return;
  int s = src[e], d = dst[e];
  f32x4 a = *reinterpret_cast<const f32x4*>(el + s * 4);
  f32x4 b = *reinterpret_cast<const f32x4*>(er + d * 4);
  f32x4 v;
#pragma unroll
  for (int i = 0; i < 4; i++){
    float x = a[i] + b[i];
    x = x > 0.f ? x : 0.2f * x;
    v[i] = __expf(x);
  }
  int p = atomicAdd(&cursor[d], 1);
  int pos = offs[d] + p;
  *reinterpret_cast<f32x4*>(ws_s + pos * 4) = v;
  src_s[pos] = s;
}

// ---- feat-row aggregation, 1 wave/node, 8-deep pipeline ----
// r10: denominator via coalesced per-lane wlane loads (+end butterfly) instead
// of redundant all-lane per-edge adds (-4 VALU/edge). FMA path unchanged.
__global__ __launch_bounds__(256) void k_aggrf(const int* __restrict__ offs,
                                               const int* __restrict__ src_s,
                                               const float* __restrict__ ws_s,
                                               const unsigned short* __restrict__ featb,
                                               unsigned short* __restrict__ fagg){
  int wave = threadIdx.x >> 6, lane = threadIdx.x & 63;
  int n = blockIdx.x * 4 + wave;
  if (n >= N_) return;
  int off0 = __builtin_amdgcn_readfirstlane(offs[n]);
  int g    = __builtin_amdgcn_readfirstlane(offs[n + 1]) - off0;
  int c0 = lane * 2;
  f32x2 acc2[4] = {};
  f32x4 wsum = {0.f, 0.f, 0.f, 0.f};

  auto FMA1 = [&](const f32x4& wv, unsigned int pv){
    f32x2 lh; lh[0] = blo(pv); lh[1] = bhi(pv);
#pragma unroll
    for (int h = 0; h < 4; h++) acc2[h] += lh * wv[h];
  };

  int i = 0;
  while (i < g){
    int blk = g - i; if (blk > 64) blk = 64;
    int idx = i + lane;
    bool va = (idx < g);
    int ssrc = va ? src_s[off0 + idx] : 0;
    f32x4 wlane = {0.f, 0.f, 0.f, 0.f};
    if (va) wlane = *reinterpret_cast<const f32x4*>(ws_s + (off0 + idx) * 4);
    wsum += wlane;                      // per-lane partial; reduced at end
    int nfull = blk >> 3;
    if (nfull){
      int sa[8]; unsigned int pa[8]; f32x4 wa[8];
#pragma unroll
      for (int u = 0; u < 8; u++) sa[u] = __shfl(ssrc, u);
#pragma unroll
      for (int u = 0; u < 8; u++) pa[u] = *reinterpret_cast<const unsigned int*>(featb + sa[u] * 128 + c0);
#pragma unroll
      for (int u = 0; u < 8; u++) wa[u] = *reinterpret_cast<const f32x4*>(ws_s + (off0 + i + u) * 4);
      for (int c = 1; c < nfull; c++){
        int sb[8]; unsigned int pb[8]; f32x4 wb[8];
#pragma unroll
        for (int u = 0; u < 8; u++) sb[u] = __shfl(ssrc, c * 8 + u);
#pragma unroll
        for (int u = 0; u < 8; u++) pb[u] = *reinterpret_cast<const unsigned int*>(featb + sb[u] * 128 + c0);
#pragma unroll
        for (int u = 0; u < 8; u++) wb[u] = *reinterpret_cast<const f32x4*>(ws_s + (off0 + i + c * 8 + u) * 4);
#pragma unroll
        for (int u = 0; u < 8; u++) FMA1(wa[u], pa[u]);
#pragma unroll
        for (int u = 0; u < 8; u++){ pa[u] = pb[u]; wa[u] = wb[u]; }
      }
#pragma unroll
      for (int u = 0; u < 8; u++) FMA1(wa[u], pa[u]);
    }
    for (int j = nfull * 8; j < blk; j++){
      int s = __shfl(ssrc, j);
      unsigned int pv = *reinterpret_cast<const unsigned int*>(featb + s * 128 + c0);
      f32x4 wv = *reinterpret_cast<const f32x4*>(ws_s + (off0 + i + j) * 4);
      FMA1(wv, pv);
    }
    i += blk;
  }

  // reduce denominator across lanes (once per node)
#pragma unroll
  for (int o = 32; o >= 1; o >>= 1){
#pragma unroll
    for (int h = 0; h < 4; h++) wsum[h] += __shfl_xor(wsum[h], o);
  }
  f32x4 rd;
#pragma unroll
  for (int h = 0; h < 4; h++) rd[h] = (wsum[h] > 0.f) ? 1.0f / wsum[h] : 0.f;
#pragma unroll
  for (int h = 0; h < 4; h++){
    unsigned int ov = (unsigned int)f2b(acc2[h][0] * rd[h]) |
                      ((unsigned int)f2b(acc2[h][1] * rd[h]) << 16);
    *reinterpret_cast<unsigned int*>(fagg + n * 512 + h * 128 + c0) = ov;
  }
}

// ---- combined GEMM: rst = F_agg @ Wfc + feat @ Wres + bias -> comb bf16 ----
// r10: BOTH phase tiles (64KB) staged upfront via global_load_lds; ONE barrier,
// then a barrier-free MFMA loop (A-loads hoist + pipeline freely).
__global__ __launch_bounds__(512) void k_gemmC(const unsigned short* __restrict__ fagg,
                                               const unsigned short* __restrict__ featb,
                                               const unsigned short* __restrict__ Wt2s,
                                               const float* __restrict__ bias,
                                               unsigned short* __restrict__ comb){
  __shared__ unsigned short wsl[2 * 128 * 128];   // 64KB: both K-phases
  char* wb = (char*)wsl;
  int tid = threadIdx.x;
  int wave = tid >> 6, lane = tid & 63;
  int lrow = lane & 15, quad = lane >> 4;
  int rowbase = blockIdx.x * 128 + wave * 16;
  int colbase = blockIdx.y * 128;             // by = head index (0..3)
  int arow = rowbase + lrow; if (arow > N_ - 1) arow = N_ - 1;
  const unsigned short* aF = fagg + arow * 512 + colbase;   // head slice
  const unsigned short* aX = featb + arow * 128;
#pragma unroll
  for (int ph = 0; ph < 2; ph++){
    const unsigned short* gt = Wt2s + (((ph << 2) | (int)blockIdx.y) << 14);
#pragma unroll
    for (int i = 0; i < 4; i++){
      int off = ((i << 3) | wave) << 9;   // 1KB chunks
      gl_lds16(gt + off + (lane << 3), wsl + (ph << 14) + off);
    }
  }
  __syncthreads();
  f32x4 acc[8] = {};
#pragma unroll
  for (int ph = 0; ph < 2; ph++){
#pragma unroll
    for (int kk = 0; kk < 4; kk++){
      Frag a;
      a.q = (ph == 0)
          ? *reinterpret_cast<const u32x4*>(aF + kk * 32 + quad * 8)
          : *reinterpret_cast<const u32x4*>(aX + kk * 32 + quad * 8);
#pragma unroll
      for (int s = 0; s < 8; s++){
        int r = s * 16 + lrow;
        int byte = (ph << 15) + ((r * 256 + kk * 64 + quad * 16) ^ ((r & 7) << 4));
        Frag b; b.q = *reinterpret_cast<const u32x4*>(wb + byte);
        acc[s] = __builtin_amdgcn_mfma_f32_16x16x32_bf16(b.v, a.v, acc[s], 0, 0, 0);
      }
    }
  }
  int gr = rowbase + lrow;
  if (gr < N_){
    unsigned short* crow = comb + gr * 512 + colbase;
#pragma unroll
    for (int s = 0; s < 8; s++){
      f32x4 bb = *reinterpret_cast<const f32x4*>(bias + colbase + s * 16 + quad * 4);
      u32x2 ov;
#pragma unroll
      for (int d = 0; d < 2; d++){
        float v0 = acc[s][2 * d]     + bb[2 * d];
        float v1 = acc[s][2 * d + 1] + bb[2 * d + 1];
        ov[d] = (unsigned int)f2b(v0) | ((unsigned int)f2b(v1) << 16);
      }
      *reinterpret_cast<u32x2*>(crow + s * 16 + quad * 4) = ov;
    }
  }
}

// ---- BN stats: 512 blocks (rows=59), wave partials + LDS block-reduce ----
__global__ __launch_bounds__(256) void k_stats(const unsigned short* __restrict__ comb,
                                               float* __restrict__ psum,
                                               float* __restrict__ psq){
  __shared__ float lsum[4][512];
  __shared__ float lsq[4][512];
  int t = threadIdx.x, lane = t & 63, rg = t >> 6;
  int c0 = lane * 8;
  const int rows = 59;
  int r0 = blockIdx.x * rows;
  int r1 = r0 + rows; if (r1 > N_) r1 = N_;
  float s[8] = {}, q[8] = {};
  for (int r = r0 + rg; r < r1; r += 4){
    u32x4 pv = *reinterpret_cast<const u32x4*>(comb + r * 512 + c0);
#pragma unroll
    for (int d = 0; d < 4; d++){
      float v0 = blo(pv[d]);
      float v1 = bhi(pv[d]);
      s[2*d]   += v0; q[2*d]   += v0 * v0;
      s[2*d+1] += v1; q[2*d+1] += v1 * v1;
    }
  }
#pragma unroll
  for (int d = 0; d < 8; d++){ lsum[rg][c0 + d] = s[d]; lsq[rg][c0 + d] = q[d]; }
  __syncthreads();
#pragma unroll
  for (int half = 0; half < 2; half++){
    int ch = t + half * 256;
    float a = lsum[0][ch] + lsum[1][ch] + lsum[2][ch] + lsum[3][ch];
    float b = lsq[0][ch] + lsq[1][ch] + lsq[2][ch] + lsq[3][ch];
    psum[blockIdx.x * 512 + ch] = a;
    psq[blockIdx.x * 512 + ch] = b;
  }
}

// ---- finalize BN: 4 blocks x 128 ch, reduce 512 block-partials ----
__global__ __launch_bounds__(128) void k_bnfin(const float* __restrict__ psum,
                                               const float* __restrict__ psq,
                                               const float* __restrict__ gamma,
                                               const float* __restrict__ beta,
                                               float* __restrict__ scale,
                                               float* __restrict__ shift){
  int ch = blockIdx.x * 128 + threadIdx.x;
  float s0 = 0.f, s1 = 0.f, s2 = 0.f, s3 = 0.f;
  float q0 = 0.f, q1 = 0.f, q2 = 0.f, q3 = 0.f;
  for (int b = 0; b < 512; b += 4){
    s0 += psum[(b    ) * 512 + ch];
    s1 += psum[(b + 1) * 512 + ch];
    s2 += psum[(b + 2) * 512 + ch];
    s3 += psum[(b + 3) * 512 + ch];
    q0 += psq[(b    ) * 512 + ch];
    q1 += psq[(b + 1) * 512 + ch];
    q2 += psq[(b + 2) * 512 + ch];
    q3 += psq[(b + 3) * 512 + ch];
  }
  float sum = (s0 + s1) + (s2 + s3);
  float sq  = (q0 + q1) + (q2 + q3);
  float mu  = sum / (float)N_;
  float var = sq / (float)N_ - mu * mu;
  float inv = rsqrtf(var + 1e-5f);
  float sc  = gamma[ch] * inv;
  scale[ch] = sc;
  shift[ch] = beta[ch] - mu * sc;
}

// ---- GEMM2: out = relu(BN(comb)) @ Wout + bout, fp32 out ----
__global__ __launch_bounds__(256) void k_gemm2(const unsigned short* __restrict__ comb,
                                               const unsigned short* __restrict__ WtOuts,
                                               const float* __restrict__ scale,
                                               const float* __restrict__ shift,
                                               const float* __restrict__ bout,
                                               float* __restrict__ out){
  __shared__ float sc[512], sh[512];
  __shared__ unsigned short wsl[128 * 128];   // 32KB
  char* wb = (char*)wsl;
  int t = threadIdx.x;
  for (int i = t; i < 512; i += 256){ sc[i] = scale[i]; sh[i] = shift[i]; }
  int wave = t >> 6, lane = t & 63, lrow = lane & 15, quad = lane >> 4;
  int rowbase = blockIdx.x * 64 + wave * 16;
  int rr = rowbase + lrow; if (rr > N_ - 1) rr = N_ - 1;
  const unsigned short* arow = comb + rr * 512;
  f32x4 acc[8] = {};
  for (int phase = 0; phase < 4; phase++){
    __syncthreads();
    {
      const unsigned short* gt = WtOuts + (phase << 14);
#pragma unroll
      for (int i = 0; i < 8; i++){
        int off = ((i << 2) | wave) << 9;
        gl_lds16(gt + off + (lane << 3), wsl + off);
      }
    }
    __syncthreads();
#pragma unroll
    for (int kk = 0; kk < 4; kk++){
      int base = phase * 128 + kk * 32 + quad * 8;
      Frag a; a.q = *reinterpret_cast<const u32x4*>(arow + base);
#pragma unroll
      for (int i2 = 0; i2 < 8; i2++){
        float x = b2f(a.us[i2]);
        x = fmaf(x, sc[base + i2], sh[base + i2]);
        a.us[i2] = f2b(fmaxf(x, 0.0f));
      }
#pragma unroll
      for (int s = 0; s < 8; s++){
        int r = s * 16 + lrow;
        int byte = (r * 256 + kk * 64 + quad * 16) ^ ((r & 7) << 4);
        Frag b; b.q = *reinterpret_cast<const u32x4*>(wb + byte);
        acc[s] = __builtin_amdgcn_mfma_f32_16x16x32_bf16(b.v, a.v, acc[s], 0, 0, 0);
      }
    }
  }
  int gr = rowbase + lrow;
  if (gr < N_){
    float* orow = out + gr * 128;
#pragma unroll
    for (int s = 0; s < 8; s++){
      int cb = s * 16 + quad * 4;
      f32x4 bb = *reinterpret_cast<const f32x4*>(bout + cb);
      f32x4 ov;
#pragma unroll
      for (int j = 0; j < 4; j++) ov[j] = acc[s][j] + bb[j];
      *reinterpret_cast<f32x4*>(orow + cb) = ov;
    }
  }
}

extern "C" void kernel_launch(void* const* d_in, const int* in_sizes, int n_in,
                              void* d_out, int out_size, void* d_ws, size_t ws_size,
                              hipStream_t stream){
  const float* feat  = (const float*)d_in[0];
  const int*   src   = (const int*)d_in[1];
  const int*   dst   = (const int*)d_in[2];
  const float* Wfc   = (const float*)d_in[3];
  const float* al    = (const float*)d_in[4];
  const float* ar    = (const float*)d_in[5];
  const float* Wres  = (const float*)d_in[6];
  const float* bias  = (const float*)d_in[7];
  const float* gamma = (const float*)d_in[8];
  const float* beta  = (const float*)d_in[9];
  const float* Wout  = (const float*)d_in[10];
  const float* bout  = (const float*)d_in[11];
  float* out = (float*)d_out;

  char* ws = (char*)d_ws;
  unsigned short* comb  = (unsigned short*)(ws + 0);           // 30,720,000
  unsigned short* fagg  = (unsigned short*)(ws + 30720000);    // 30,720,000
  unsigned short* Wt2s  = (unsigned short*)(ws + 61440000);    //    262,144
  unsigned short* WtOuts= (unsigned short*)(ws + 61702144);    //    131,072
  float*          el    = (float*)(ws + 61833216);             //    480,000
  float*          er    = (float*)(ws + 62313216);             //    480,000
  float*          ws_s  = (float*)(ws + 62793216);             //  7,680,000
  int*            offs  = (int*)(ws + 70473216);               //    120,064
  int*            counts= (int*)(ws + 70593280);               //    120,000
  int*            cursor= (int*)(ws + 70713280);               //    120,000
  int*            src_s = (int*)(ws + 70833280);               //  1,920,000
  float*          Pbuf  = (float*)(ws + 72753280);             //      8,192 (P)
  float*          scale = (float*)(ws + 73801856);             //      2,048
  float*          shift = (float*)(ws + 73803904);             //      2,048
  unsigned short* featb = (unsigned short*)(ws + 73805952);    //  7,680,000
  // stats partials overlay the dead ws_s region (dead after k_aggrf):
  float*          psumS = (float*)(ws + 62793216);             //  1,048,576
  float*          psqS  = (float*)(ws + 63841792);             //  1,048,576

  k_initconv<<<260, 256, 0, stream>>>(Wfc, Wres, Wout, al, ar, Wt2s, WtOuts, Pbuf,
                                      counts, cursor);
  k_elhist<<<1875 + (N_ + 31) / 32, 256, 0, stream>>>(feat, Pbuf, dst, counts,
                                                      el, er, featb);
  k_scan<<<1, 1024, 0, stream>>>(counts, offs);
  k_edge<<<(E_ + 255) / 256, 256, 0, stream>>>(src, dst, el, er, ws_s, src_s, offs, cursor);
  k_aggrf<<<(N_ + 3) / 4, 256, 0, stream>>>(offs, src_s, ws_s, featb, fagg);
  dim3 gC((N_ + 127) / 128, 4);
  k_gemmC<<<gC, 512, 0, stream>>>(fagg, featb, Wt2s, bias, comb);
  k_stats<<<512, 256, 0, stream>>>(comb, psumS, psqS);
  k_bnfin<<<4, 128, 0, stream>>>(psumS, psqS, gamma, beta, scale, shift);
  k_gemm2<<<(N_ + 63) / 64, 256, 0, stream>>>(comb, WtOuts, scale, shift, bout, out);
}

// Round 12
// 253.697 us; speedup vs baseline: 1.1240x; 1.0386x over previous
//
#include <hip/hip_runtime.h>

#define N_  30000
#define E_  480000

typedef short short8 __attribute__((ext_vector_type(8)));
typedef float f32x4  __attribute__((ext_vector_type(4)));
typedef float f32x2  __attribute__((ext_vector_type(2)));
typedef unsigned int u32x4 __attribute__((ext_vector_type(4)));
typedef unsigned int u32x2 __attribute__((ext_vector_type(2)));
typedef int i32x4 __attribute__((ext_vector_type(4)));
union Frag { u32x4 q; short8 v; unsigned short us[8]; };

__device__ __forceinline__ float b2f(unsigned short u){
  union { unsigned int i; float f; } v; v.i = ((unsigned int)u) << 16; return v.f;
}
__device__ __forceinline__ float blo(unsigned int u){
  union { unsigned int i; float f; } v; v.i = u << 16; return v.f;
}
__device__ __forceinline__ float bhi(unsigned int u){
  union { unsigned int i; float f; } v; v.i = u & 0xffff0000u; return v.f;
}
__device__ __forceinline__ unsigned short f2b(float f){
  union { float f; unsigned int u; } v; v.f = f;
  unsigned int u = v.u;
  return (unsigned short)((u + 0x7fffu + ((u >> 16) & 1u)) >> 16);
}
// direct global->LDS 16B copy (dest = wave-uniform base + lane*16)
__device__ __forceinline__ void gl_lds16(const unsigned short* g, unsigned short* l){
  __builtin_amdgcn_global_load_lds(
      (const __attribute__((address_space(1))) unsigned int*)g,
      (__attribute__((address_space(3))) unsigned int*)l, 16, 0, 0);
}

// ---- init scratch + PRE-SWIZZLED weight LDS-images + P fold ----
__global__ void k_initconv(const float* __restrict__ Wfc, const float* __restrict__ Wres,
                           const float* __restrict__ Wout,
                           const float* __restrict__ al, const float* __restrict__ ar,
                           unsigned short* __restrict__ Wt2s, unsigned short* __restrict__ WtOuts,
                           float* __restrict__ P,
                           int* __restrict__ counts, int* __restrict__ cursor,
                           float* __restrict__ gsum, float* __restrict__ gsq){
  int bx = blockIdx.x;
  if (bx >= 256){
    int idx = (bx - 256) * 256 + threadIdx.x;   // 0..1023
    if (idx < 1024){
      int k = idx >> 3, q = idx & 7;
      int h = q & 3;
      const float* a = (q < 4) ? al : ar;
      const float* wr = Wfc + k * 512 + h * 128;
      const float* av = a + h * 128;
      float s = 0.f;
#pragma unroll 4
      for (int d = 0; d < 128; d++) s += wr[d] * av[d];
      P[k * 8 + q] = s;
    }
    return;
  }
  int gid = bx * 256 + threadIdx.x;
  const int stride = 256 * 256;
  if (gid < N_){ counts[gid] = 0; cursor[gid] = 0; }
  if (gid < 512){ gsum[gid] = 0.f; gsq[gid] = 0.f; }
  const int total1 = 131072;               // Wt2s elements
  const int total2 = 65536;                // WtOuts elements
  for (int i = gid; i < total1 + total2; i += stride){
    if (i < total1){
      int tile = i >> 14, E = i & 16383;
      int ph = tile >> 2, by = tile & 3;
      int col = E >> 7, remE = E & 127;
      int unit = (remE >> 3) ^ (col & 7);
      int k = unit * 8 + (remE & 7);
      int c = by * 128 + col;
      float v = ph ? Wres[k * 512 + c] : Wfc[k * 512 + c];
      Wt2s[i] = f2b(v);
    } else {
      int j = i - total1;
      int ph = j >> 14, E = j & 16383;
      int col = E >> 7, remE = E & 127;
      int unit = (remE >> 3) ^ (col & 7);
      int k = unit * 8 + (remE & 7);
      WtOuts[j] = f2b(Wout[(ph * 128 + k) * 128 + col]);
    }
  }
}

// ---- FUSED: dst histogram (blocks 0..1874) + el/er + featb (blocks 1875+) ----
__global__ __launch_bounds__(256) void k_elhist(const float* __restrict__ feat,
                                                const float* __restrict__ P,
                                                const int* __restrict__ dst,
                                                int* __restrict__ counts,
                                                float* __restrict__ el, float* __restrict__ er,
                                                unsigned short* __restrict__ featb){
  __shared__ float sF[32 * 132];
  __shared__ float sP[1024];
  int bx = blockIdx.x;
  if (bx < 1875){
    int e = bx * 256 + threadIdx.x;
    if (e < E_) atomicAdd(&counts[dst[e]], 1);
    return;
  }
  int t = threadIdx.x;
  int n0 = (bx - 1875) * 32;
  *reinterpret_cast<f32x4*>(&sP[t * 4]) = *reinterpret_cast<const f32x4*>(P + t * 4);
#pragma unroll
  for (int i = 0; i < 4; i++){
    int c = t + i * 256;
    int r = c >> 5, cw = (c & 31) * 4;
    int gn = n0 + r;
    f32x4 v = {0.f, 0.f, 0.f, 0.f};
    if (gn < N_) v = *reinterpret_cast<const f32x4*>(feat + gn * 128 + cw);
    *reinterpret_cast<f32x4*>(&sF[r * 132 + cw]) = v;
  }
  __syncthreads();
#pragma unroll
  for (int i = 0; i < 8; i++){
    int c = t + i * 256;                 // dword id 0..2047
    int r = c >> 6, cw = (c & 63) * 2;
    int gn = n0 + r;
    if (gn < N_){
      float v0 = sF[r * 132 + cw], v1 = sF[r * 132 + cw + 1];
      unsigned int pv = (unsigned int)f2b(v0) | ((unsigned int)f2b(v1) << 16);
      *reinterpret_cast<unsigned int*>(featb + gn * 128 + cw) = pv;
    }
  }
  int node = t >> 3, q = t & 7;
  int gn = n0 + node;
  const float* fr = &sF[node * 132];
  float s = 0.f;
#pragma unroll 2
  for (int k = 0; k < 128; k += 4){
    f32x4 fv = *reinterpret_cast<const f32x4*>(fr + k);
#pragma unroll
    for (int j = 0; j < 4; j++) s += fv[j] * sP[(k + j) * 8 + q];
  }
  if (gn < N_){
    if (q < 4) el[gn * 4 + q] = s;
    else       er[gn * 4 + (q - 4)] = s;
  }
}

// ---- exclusive scan -> offs[0..N_], int4-vectorized loads ----
__global__ __launch_bounds__(1024) void k_scan(const int* __restrict__ counts,
                                               int* __restrict__ offs){
  __shared__ int wsum[16];
  int t = threadIdx.x;
  int lane = t & 63, w = t >> 6;
  int base = t * 32;
  int vals[32];
  int s = 0;
  bool inb = (base < N_);
#pragma unroll
  for (int jj = 0; jj < 8; jj++){
    i32x4 cv = {0, 0, 0, 0};
    if (inb) cv = *reinterpret_cast<const i32x4*>(counts + base + jj * 4);
#pragma unroll
    for (int m = 0; m < 4; m++){
      int idx = base + jj * 4 + m;
      int v = (idx < N_) ? cv[m] : 0;
      vals[jj * 4 + m] = s;
      s += v;
    }
  }
  int x = s;
  for (int o = 1; o < 64; o <<= 1){
    int y = __shfl_up(x, o);
    if (lane >= o) x += y;
  }
  if (lane == 63) wsum[w] = x;
  __syncthreads();
  if (t < 16){
    int y = wsum[t];
    for (int o = 1; o < 16; o <<= 1){
      int z = __shfl_up(y, o, 16);
      if (t >= o) y += z;
    }
    wsum[t] = y;
  }
  __syncthreads();
  int wbase = (w > 0) ? wsum[w - 1] : 0;
  int ex = wbase + x - s;
#pragma unroll
  for (int j = 0; j < 32; j++){
    int idx = base + j;
    if (idx <= N_) offs[idx] = ex + vals[j];
  }
}

// ---- per-edge unnormalized softmax weight + CSR scatter ----
__global__ void k_edge(const int* __restrict__ src, const int* __restrict__ dst,
                       const float* __restrict__ el, const float* __restrict__ er,
                       float* __restrict__ ws_s, int* __restrict__ src_s,
                       const int* __restrict__ offs, int* __restrict__ cursor){
  int e = blockIdx.x * 256 + threadIdx.x;
  if (e >= E_) return;
  int s = src[e], d = dst[e];
  f32x4 a = *reinterpret_cast<const f32x4*>(el + s * 4);
  f32x4 b = *reinterpret_cast<const f32x4*>(er + d * 4);
  f32x4 v;
#pragma unroll
  for (int i = 0; i < 4; i++){
    float x = a[i] + b[i];
    x = x > 0.f ? x : 0.2f * x;
    v[i] = __expf(x);
  }
  int p = atomicAdd(&cursor[d], 1);
  int pos = offs[d] + p;
  *reinterpret_cast<f32x4*>(ws_s + pos * 4) = v;
  src_s[pos] = s;
}

// ---- feat-row aggregation, 1 wave/node, 8-deep pipeline ----
__global__ __launch_bounds__(256) void k_aggrf(const int* __restrict__ offs,
                                               const int* __restrict__ src_s,
                                               const float* __restrict__ ws_s,
                                               const unsigned short* __restrict__ featb,
                                               unsigned short* __restrict__ fagg){
  int wave = threadIdx.x >> 6, lane = threadIdx.x & 63;
  int n = blockIdx.x * 4 + wave;
  if (n >= N_) return;
  int off0 = __builtin_amdgcn_readfirstlane(offs[n]);
  int g    = __builtin_amdgcn_readfirstlane(offs[n + 1]) - off0;
  int c0 = lane * 2;
  f32x2 acc2[4] = {};
  f32x4 wsum = {0.f, 0.f, 0.f, 0.f};

  auto FMA1 = [&](const f32x4& wv, unsigned int pv){
    f32x2 lh; lh[0] = blo(pv); lh[1] = bhi(pv);
#pragma unroll
    for (int h = 0; h < 4; h++) acc2[h] += lh * wv[h];
  };

  int i = 0;
  while (i < g){
    int blk = g - i; if (blk > 64) blk = 64;
    int idx = i + lane;
    bool va = (idx < g);
    int ssrc = va ? src_s[off0 + idx] : 0;
    f32x4 wlane = {0.f, 0.f, 0.f, 0.f};
    if (va) wlane = *reinterpret_cast<const f32x4*>(ws_s + (off0 + idx) * 4);
    wsum += wlane;                      // per-lane partial; reduced at end
    int nfull = blk >> 3;
    if (nfull){
      int sa[8]; unsigned int pa[8]; f32x4 wa[8];
#pragma unroll
      for (int u = 0; u < 8; u++) sa[u] = __shfl(ssrc, u);
#pragma unroll
      for (int u = 0; u < 8; u++) pa[u] = *reinterpret_cast<const unsigned int*>(featb + sa[u] * 128 + c0);
#pragma unroll
      for (int u = 0; u < 8; u++) wa[u] = *reinterpret_cast<const f32x4*>(ws_s + (off0 + i + u) * 4);
      for (int c = 1; c < nfull; c++){
        int sb[8]; unsigned int pb[8]; f32x4 wb[8];
#pragma unroll
        for (int u = 0; u < 8; u++) sb[u] = __shfl(ssrc, c * 8 + u);
#pragma unroll
        for (int u = 0; u < 8; u++) pb[u] = *reinterpret_cast<const unsigned int*>(featb + sb[u] * 128 + c0);
#pragma unroll
        for (int u = 0; u < 8; u++) wb[u] = *reinterpret_cast<const f32x4*>(ws_s + (off0 + i + c * 8 + u) * 4);
#pragma unroll
        for (int u = 0; u < 8; u++) FMA1(wa[u], pa[u]);
#pragma unroll
        for (int u = 0; u < 8; u++){ pa[u] = pb[u]; wa[u] = wb[u]; }
      }
#pragma unroll
      for (int u = 0; u < 8; u++) FMA1(wa[u], pa[u]);
    }
    for (int j = nfull * 8; j < blk; j++){
      int s = __shfl(ssrc, j);
      unsigned int pv = *reinterpret_cast<const unsigned int*>(featb + s * 128 + c0);
      f32x4 wv = *reinterpret_cast<const f32x4*>(ws_s + (off0 + i + j) * 4);
      FMA1(wv, pv);
    }
    i += blk;
  }

  // reduce denominator across lanes (once per node)
#pragma unroll
  for (int o = 32; o >= 1; o >>= 1){
#pragma unroll
    for (int h = 0; h < 4; h++) wsum[h] += __shfl_xor(wsum[h], o);
  }
  f32x4 rd;
#pragma unroll
  for (int h = 0; h < 4; h++) rd[h] = (wsum[h] > 0.f) ? 1.0f / wsum[h] : 0.f;
#pragma unroll
  for (int h = 0; h < 4; h++){
    unsigned int ov = (unsigned int)f2b(acc2[h][0] * rd[h]) |
                      ((unsigned int)f2b(acc2[h][1] * rd[h]) << 16);
    *reinterpret_cast<unsigned int*>(fagg + n * 512 + h * 128 + c0) = ov;
  }
}

// ---- combined GEMM: rst = F_agg @ Wfc + feat @ Wres + bias -> comb bf16 ----
__global__ __launch_bounds__(512) void k_gemmC(const unsigned short* __restrict__ fagg,
                                               const unsigned short* __restrict__ featb,
                                               const unsigned short* __restrict__ Wt2s,
                                               const float* __restrict__ bias,
                                               unsigned short* __restrict__ comb){
  __shared__ unsigned short wsl[2 * 128 * 128];   // 64KB: both K-phases
  char* wb = (char*)wsl;
  int tid = threadIdx.x;
  int wave = tid >> 6, lane = tid & 63;
  int lrow = lane & 15, quad = lane >> 4;
  int rowbase = blockIdx.x * 128 + wave * 16;
  int colbase = blockIdx.y * 128;             // by = head index (0..3)
  int arow = rowbase + lrow; if (arow > N_ - 1) arow = N_ - 1;
  const unsigned short* aF = fagg + arow * 512 + colbase;   // head slice
  const unsigned short* aX = featb + arow * 128;
#pragma unroll
  for (int ph = 0; ph < 2; ph++){
    const unsigned short* gt = Wt2s + (((ph << 2) | (int)blockIdx.y) << 14);
#pragma unroll
    for (int i = 0; i < 4; i++){
      int off = ((i << 3) | wave) << 9;   // 1KB chunks
      gl_lds16(gt + off + (lane << 3), wsl + (ph << 14) + off);
    }
  }
  __syncthreads();
  f32x4 acc[8] = {};
#pragma unroll
  for (int ph = 0; ph < 2; ph++){
#pragma unroll
    for (int kk = 0; kk < 4; kk++){
      Frag a;
      a.q = (ph == 0)
          ? *reinterpret_cast<const u32x4*>(aF + kk * 32 + quad * 8)
          : *reinterpret_cast<const u32x4*>(aX + kk * 32 + quad * 8);
#pragma unroll
      for (int s = 0; s < 8; s++){
        int r = s * 16 + lrow;
        int byte = (ph << 15) + ((r * 256 + kk * 64 + quad * 16) ^ ((r & 7) << 4));
        Frag b; b.q = *reinterpret_cast<const u32x4*>(wb + byte);
        acc[s] = __builtin_amdgcn_mfma_f32_16x16x32_bf16(b.v, a.v, acc[s], 0, 0, 0);
      }
    }
  }
  int gr = rowbase + lrow;
  if (gr < N_){
    unsigned short* crow = comb + gr * 512 + colbase;
#pragma unroll
    for (int s = 0; s < 8; s++){
      f32x4 bb = *reinterpret_cast<const f32x4*>(bias + colbase + s * 16 + quad * 4);
      u32x2 ov;
#pragma unroll
      for (int d = 0; d < 2; d++){
        float v0 = acc[s][2 * d]     + bb[2 * d];
        float v1 = acc[s][2 * d + 1] + bb[2 * d + 1];
        ov[d] = (unsigned int)f2b(v0) | ((unsigned int)f2b(v1) << 16);
      }
      *reinterpret_cast<u32x2*>(crow + s * 16 + quad * 4) = ov;
    }
  }
}

// ---- BN stats: 512 blocks (rows=59), block reduce + ATOMIC finalize ----
// r12: final per-channel sums accumulate straight into gsum/gsq[512] via
// device atomics (replaces 1MB partials + the k_bnfin dispatch).
__global__ __launch_bounds__(256) void k_stats(const unsigned short* __restrict__ comb,
                                               float* __restrict__ gsum,
                                               float* __restrict__ gsq){
  __shared__ float lsum[4][512];
  __shared__ float lsq[4][512];
  int t = threadIdx.x, lane = t & 63, rg = t >> 6;
  int c0 = lane * 8;
  const int rows = 59;
  int r0 = blockIdx.x * rows;
  int r1 = r0 + rows; if (r1 > N_) r1 = N_;
  float s[8] = {}, q[8] = {};
  for (int r = r0 + rg; r < r1; r += 4){
    u32x4 pv = *reinterpret_cast<const u32x4*>(comb + r * 512 + c0);
#pragma unroll
    for (int d = 0; d < 4; d++){
      float v0 = blo(pv[d]);
      float v1 = bhi(pv[d]);
      s[2*d]   += v0; q[2*d]   += v0 * v0;
      s[2*d+1] += v1; q[2*d+1] += v1 * v1;
    }
  }
#pragma unroll
  for (int d = 0; d < 8; d++){ lsum[rg][c0 + d] = s[d]; lsq[rg][c0 + d] = q[d]; }
  __syncthreads();
#pragma unroll
  for (int half = 0; half < 2; half++){
    int ch = t + half * 256;
    float a = lsum[0][ch] + lsum[1][ch] + lsum[2][ch] + lsum[3][ch];
    float b = lsq[0][ch] + lsq[1][ch] + lsq[2][ch] + lsq[3][ch];
    atomicAdd(&gsum[ch], a);
    atomicAdd(&gsq[ch], b);
  }
}

// ---- GEMM2: out = relu(BN(comb)) @ Wout + bout, fp32 out ----
// r12: scale/shift computed inline from gsum/gsq (k_bnfin folded in).
__global__ __launch_bounds__(256) void k_gemm2(const unsigned short* __restrict__ comb,
                                               const unsigned short* __restrict__ WtOuts,
                                               const float* __restrict__ gsum,
                                               const float* __restrict__ gsq,
                                               const float* __restrict__ gamma,
                                               const float* __restrict__ beta,
                                               const float* __restrict__ bout,
                                               float* __restrict__ out){
  __shared__ float sc[512], sh[512];
  __shared__ unsigned short wsl[128 * 128];   // 32KB
  char* wb = (char*)wsl;
  int t = threadIdx.x;
  for (int i = t; i < 512; i += 256){
    float sum = gsum[i], sq = gsq[i];
    float mu  = sum * (1.0f / (float)N_);
    float var = sq * (1.0f / (float)N_) - mu * mu;
    float inv = rsqrtf(var + 1e-5f);
    float scv = gamma[i] * inv;
    sc[i] = scv;
    sh[i] = beta[i] - mu * scv;
  }
  int wave = t >> 6, lane = t & 63, lrow = lane & 15, quad = lane >> 4;
  int rowbase = blockIdx.x * 64 + wave * 16;
  int rr = rowbase + lrow; if (rr > N_ - 1) rr = N_ - 1;
  const unsigned short* arow = comb + rr * 512;
  f32x4 acc[8] = {};
  for (int phase = 0; phase < 4; phase++){
    __syncthreads();
    {
      const unsigned short* gt = WtOuts + (phase << 14);
#pragma unroll
      for (int i = 0; i < 8; i++){
        int off = ((i << 2) | wave) << 9;
        gl_lds16(gt + off + (lane << 3), wsl + off);
      }
    }
    __syncthreads();
#pragma unroll
    for (int kk = 0; kk < 4; kk++){
      int base = phase * 128 + kk * 32 + quad * 8;
      Frag a; a.q = *reinterpret_cast<const u32x4*>(arow + base);
#pragma unroll
      for (int i2 = 0; i2 < 8; i2++){
        float x = b2f(a.us[i2]);
        x = fmaf(x, sc[base + i2], sh[base + i2]);
        a.us[i2] = f2b(fmaxf(x, 0.0f));
      }
#pragma unroll
      for (int s = 0; s < 8; s++){
        int r = s * 16 + lrow;
        int byte = (r * 256 + kk * 64 + quad * 16) ^ ((r & 7) << 4);
        Frag b; b.q = *reinterpret_cast<const u32x4*>(wb + byte);
        acc[s] = __builtin_amdgcn_mfma_f32_16x16x32_bf16(b.v, a.v, acc[s], 0, 0, 0);
      }
    }
  }
  int gr = rowbase + lrow;
  if (gr < N_){
    float* orow = out + gr * 128;
#pragma unroll
    for (int s = 0; s < 8; s++){
      int cb = s * 16 + quad * 4;
      f32x4 bb = *reinterpret_cast<const f32x4*>(bout + cb);
      f32x4 ov;
#pragma unroll
      for (int j = 0; j < 4; j++) ov[j] = acc[s][j] + bb[j];
      *reinterpret_cast<f32x4*>(orow + cb) = ov;
    }
  }
}

extern "C" void kernel_launch(void* const* d_in, const int* in_sizes, int n_in,
                              void* d_out, int out_size, void* d_ws, size_t ws_size,
                              hipStream_t stream){
  const float* feat  = (const float*)d_in[0];
  const int*   src   = (const int*)d_in[1];
  const int*   dst   = (const int*)d_in[2];
  const float* Wfc   = (const float*)d_in[3];
  const float* al    = (const float*)d_in[4];
  const float* ar    = (const float*)d_in[5];
  const float* Wres  = (const float*)d_in[6];
  const float* bias  = (const float*)d_in[7];
  const float* gamma = (const float*)d_in[8];
  const float* beta  = (const float*)d_in[9];
  const float* Wout  = (const float*)d_in[10];
  const float* bout  = (const float*)d_in[11];
  float* out = (float*)d_out;

  char* ws = (char*)d_ws;
  unsigned short* comb  = (unsigned short*)(ws + 0);           // 30,720,000
  unsigned short* fagg  = (unsigned short*)(ws + 30720000);    // 30,720,000
  unsigned short* Wt2s  = (unsigned short*)(ws + 61440000);    //    262,144
  unsigned short* WtOuts= (unsigned short*)(ws + 61702144);    //    131,072
  float*          el    = (float*)(ws + 61833216);             //    480,000
  float*          er    = (float*)(ws + 62313216);             //    480,000
  float*          ws_s  = (float*)(ws + 62793216);             //  7,680,000
  int*            offs  = (int*)(ws + 70473216);               //    120,064
  int*            counts= (int*)(ws + 70593280);               //    120,000
  int*            cursor= (int*)(ws + 70713280);               //    120,000
  int*            src_s = (int*)(ws + 70833280);               //  1,920,000
  float*          Pbuf  = (float*)(ws + 72753280);             //      8,192 (P)
  float*          gsum  = (float*)(ws + 73801856);             //      2,048 (512 f32)
  float*          gsq   = (float*)(ws + 73803904);             //      2,048 (512 f32)
  unsigned short* featb = (unsigned short*)(ws + 73805952);    //  7,680,000

  k_initconv<<<260, 256, 0, stream>>>(Wfc, Wres, Wout, al, ar, Wt2s, WtOuts, Pbuf,
                                      counts, cursor, gsum, gsq);
  k_elhist<<<1875 + (N_ + 31) / 32, 256, 0, stream>>>(feat, Pbuf, dst, counts,
                                                      el, er, featb);
  k_scan<<<1, 1024, 0, stream>>>(counts, offs);
  k_edge<<<(E_ + 255) / 256, 256, 0, stream>>>(src, dst, el, er, ws_s, src_s, offs, cursor);
  k_aggrf<<<(N_ + 3) / 4, 256, 0, stream>>>(offs, src_s, ws_s, featb, fagg);
  dim3 gC((N_ + 127) / 128, 4);
  k_gemmC<<<gC, 512, 0, stream>>>(fagg, featb, Wt2s, bias, comb);
  k_stats<<<512, 256, 0, stream>>>(comb, gsum, gsq);
  k_gemm2<<<(N_ + 63) / 64, 256, 0, stream>>>(comb, WtOuts, gsum, gsq, gamma, beta,
                                              bout, out);
}

// Round 15
// 245.824 us; speedup vs baseline: 1.1600x; 1.0320x over previous
//
#include <hip/hip_runtime.h>

#define N_  30000
#define E_  480000

typedef short short8 __attribute__((ext_vector_type(8)));
typedef float f32x4  __attribute__((ext_vector_type(4)));
typedef float f32x2  __attribute__((ext_vector_type(2)));
typedef unsigned int u32x4 __attribute__((ext_vector_type(4)));
typedef unsigned int u32x2 __attribute__((ext_vector_type(2)));
typedef int i32x4 __attribute__((ext_vector_type(4)));
union Frag { u32x4 q; short8 v; unsigned short us[8]; };

__device__ __forceinline__ float b2f(unsigned short u){
  union { unsigned int i; float f; } v; v.i = ((unsigned int)u) << 16; return v.f;
}
__device__ __forceinline__ float blo(unsigned int u){
  union { unsigned int i; float f; } v; v.i = u << 16; return v.f;
}
__device__ __forceinline__ float bhi(unsigned int u){
  union { unsigned int i; float f; } v; v.i = u & 0xffff0000u; return v.f;
}
__device__ __forceinline__ unsigned short f2b(float f){
  union { float f; unsigned int u; } v; v.f = f;
  unsigned int u = v.u;
  return (unsigned short)((u + 0x7fffu + ((u >> 16) & 1u)) >> 16);
}
// direct global->LDS 16B copy (dest = wave-uniform base + lane*16)
__device__ __forceinline__ void gl_lds16(const unsigned short* g, unsigned short* l){
  __builtin_amdgcn_global_load_lds(
      (const __attribute__((address_space(1))) unsigned int*)g,
      (__attribute__((address_space(3))) unsigned int*)l, 16, 0, 0);
}

// ---- init scratch + PRE-SWIZZLED weight LDS-images + P fold ----
__global__ void k_initconv(const float* __restrict__ Wfc, const float* __restrict__ Wres,
                           const float* __restrict__ Wout,
                           const float* __restrict__ al, const float* __restrict__ ar,
                           unsigned short* __restrict__ Wt2s, unsigned short* __restrict__ WtOuts,
                           float* __restrict__ P,
                           int* __restrict__ counts, int* __restrict__ cursor,
                           float* __restrict__ gsum, float* __restrict__ gsq){
  int bx = blockIdx.x;
  if (bx >= 256){
    int idx = (bx - 256) * 256 + threadIdx.x;   // 0..1023
    if (idx < 1024){
      int k = idx >> 3, q = idx & 7;
      int h = q & 3;
      const float* a = (q < 4) ? al : ar;
      const float* wr = Wfc + k * 512 + h * 128;
      const float* av = a + h * 128;
      float s = 0.f;
#pragma unroll 4
      for (int d = 0; d < 128; d++) s += wr[d] * av[d];
      P[k * 8 + q] = s;
    }
    return;
  }
  int gid = bx * 256 + threadIdx.x;
  const int stride = 256 * 256;
  if (gid < N_){ counts[gid] = 0; cursor[gid] = 0; }
  if (gid < 512){ gsum[gid] = 0.f; gsq[gid] = 0.f; }
  const int total1 = 131072;               // Wt2s elements
  const int total2 = 65536;                // WtOuts elements
  for (int i = gid; i < total1 + total2; i += stride){
    if (i < total1){
      int tile = i >> 14, E = i & 16383;
      int ph = tile >> 2, by = tile & 3;
      int col = E >> 7, remE = E & 127;
      int unit = (remE >> 3) ^ (col & 7);
      int k = unit * 8 + (remE & 7);
      int c = by * 128 + col;
      float v = ph ? Wres[k * 512 + c] : Wfc[k * 512 + c];
      Wt2s[i] = f2b(v);
    } else {
      int j = i - total1;
      int ph = j >> 14, E = j & 16383;
      int col = E >> 7, remE = E & 127;
      int unit = (remE >> 3) ^ (col & 7);
      int k = unit * 8 + (remE & 7);
      WtOuts[j] = f2b(Wout[(ph * 128 + k) * 128 + col]);
    }
  }
}

// ---- FUSED: dst histogram (blocks 0..1874) + el/er + featb (blocks 1875+) ----
__global__ __launch_bounds__(256) void k_elhist(const float* __restrict__ feat,
                                                const float* __restrict__ P,
                                                const int* __restrict__ dst,
                                                int* __restrict__ counts,
                                                float* __restrict__ el, float* __restrict__ er,
                                                unsigned short* __restrict__ featb){
  __shared__ float sF[32 * 132];
  __shared__ float sP[1024];
  int bx = blockIdx.x;
  if (bx < 1875){
    int e = bx * 256 + threadIdx.x;
    if (e < E_) atomicAdd(&counts[dst[e]], 1);
    return;
  }
  int t = threadIdx.x;
  int n0 = (bx - 1875) * 32;
  *reinterpret_cast<f32x4*>(&sP[t * 4]) = *reinterpret_cast<const f32x4*>(P + t * 4);
#pragma unroll
  for (int i = 0; i < 4; i++){
    int c = t + i * 256;
    int r = c >> 5, cw = (c & 31) * 4;
    int gn = n0 + r;
    f32x4 v = {0.f, 0.f, 0.f, 0.f};
    if (gn < N_) v = *reinterpret_cast<const f32x4*>(feat + gn * 128 + cw);
    *reinterpret_cast<f32x4*>(&sF[r * 132 + cw]) = v;
  }
  __syncthreads();
#pragma unroll
  for (int i = 0; i < 8; i++){
    int c = t + i * 256;                 // dword id 0..2047
    int r = c >> 6, cw = (c & 63) * 2;
    int gn = n0 + r;
    if (gn < N_){
      float v0 = sF[r * 132 + cw], v1 = sF[r * 132 + cw + 1];
      unsigned int pv = (unsigned int)f2b(v0) | ((unsigned int)f2b(v1) << 16);
      *reinterpret_cast<unsigned int*>(featb + gn * 128 + cw) = pv;
    }
  }
  int node = t >> 3, q = t & 7;
  int gn = n0 + node;
  const float* fr = &sF[node * 132];
  float s = 0.f;
#pragma unroll 2
  for (int k = 0; k < 128; k += 4){
    f32x4 fv = *reinterpret_cast<const f32x4*>(fr + k);
#pragma unroll
    for (int j = 0; j < 4; j++) s += fv[j] * sP[(k + j) * 8 + q];
  }
  if (gn < N_){
    if (q < 4) el[gn * 4 + q] = s;
    else       er[gn * 4 + (q - 4)] = s;
  }
}

// ---- exclusive scan -> offs[0..N_], int4-vectorized loads ----
__global__ __launch_bounds__(1024) void k_scan(const int* __restrict__ counts,
                                               int* __restrict__ offs){
  __shared__ int wsum[16];
  int t = threadIdx.x;
  int lane = t & 63, w = t >> 6;
  int base = t * 32;
  int vals[32];
  int s = 0;
  bool inb = (base < N_);
#pragma unroll
  for (int jj = 0; jj < 8; jj++){
    i32x4 cv = {0, 0, 0, 0};
    if (inb) cv = *reinterpret_cast<const i32x4*>(counts + base + jj * 4);
#pragma unroll
    for (int m = 0; m < 4; m++){
      int idx = base + jj * 4 + m;
      int v = (idx < N_) ? cv[m] : 0;
      vals[jj * 4 + m] = s;
      s += v;
    }
  }
  int x = s;
  for (int o = 1; o < 64; o <<= 1){
    int y = __shfl_up(x, o);
    if (lane >= o) x += y;
  }
  if (lane == 63) wsum[w] = x;
  __syncthreads();
  if (t < 16){
    int y = wsum[t];
    for (int o = 1; o < 16; o <<= 1){
      int z = __shfl_up(y, o, 16);
      if (t >= o) y += z;
    }
    wsum[t] = y;
  }
  __syncthreads();
  int wbase = (w > 0) ? wsum[w - 1] : 0;
  int ex = wbase + x - s;
#pragma unroll
  for (int j = 0; j < 32; j++){
    int idx = base + j;
    if (idx <= N_) offs[idx] = ex + vals[j];
  }
}

// ---- per-edge unnormalized softmax weight + CSR scatter ----
__global__ void k_edge(const int* __restrict__ src, const int* __restrict__ dst,
                       const float* __restrict__ el, const float* __restrict__ er,
                       float* __restrict__ ws_s, int* __restrict__ src_s,
                       const int* __restrict__ offs, int* __restrict__ cursor){
  int e = blockIdx.x * 256 + threadIdx.x;
  if (e >= E_) return;
  int s = src[e], d = dst[e];
  f32x4 a = *reinterpret_cast<const f32x4*>(el + s * 4);
  f32x4 b = *reinterpret_cast<const f32x4*>(er + d * 4);
  f32x4 v;
#pragma unroll
  for (int i = 0; i < 4; i++){
    float x = a[i] + b[i];
    x = x > 0.f ? x : 0.2f * x;
    v[i] = __expf(x);
  }
  int p = atomicAdd(&cursor[d], 1);
  int pos = offs[d] + p;
  *reinterpret_cast<f32x4*>(ws_s + pos * 4) = v;
  src_s[pos] = s;
}

// ---- feat-row aggregation, 1 wave/node, 8-deep pipeline ----
__global__ __launch_bounds__(256) void k_aggrf(const int* __restrict__ offs,
                                               const int* __restrict__ src_s,
                                               const float* __restrict__ ws_s,
                                               const unsigned short* __restrict__ featb,
                                               unsigned short* __restrict__ fagg){
  int wave = threadIdx.x >> 6, lane = threadIdx.x & 63;
  int n = blockIdx.x * 4 + wave;
  if (n >= N_) return;
  int off0 = __builtin_amdgcn_readfirstlane(offs[n]);
  int g    = __builtin_amdgcn_readfirstlane(offs[n + 1]) - off0;
  int c0 = lane * 2;
  f32x2 acc2[4] = {};
  f32x4 wsum = {0.f, 0.f, 0.f, 0.f};

  auto FMA1 = [&](const f32x4& wv, unsigned int pv){
    f32x2 lh; lh[0] = blo(pv); lh[1] = bhi(pv);
#pragma unroll
    for (int h = 0; h < 4; h++) acc2[h] += lh * wv[h];
  };

  int i = 0;
  while (i < g){
    int blk = g - i; if (blk > 64) blk = 64;
    int idx = i + lane;
    bool va = (idx < g);
    int ssrc = va ? src_s[off0 + idx] : 0;
    f32x4 wlane = {0.f, 0.f, 0.f, 0.f};
    if (va) wlane = *reinterpret_cast<const f32x4*>(ws_s + (off0 + idx) * 4);
    wsum += wlane;                      // per-lane partial; reduced at end
    int nfull = blk >> 3;
    if (nfull){
      int sa[8]; unsigned int pa[8]; f32x4 wa[8];
#pragma unroll
      for (int u = 0; u < 8; u++) sa[u] = __shfl(ssrc, u);
#pragma unroll
      for (int u = 0; u < 8; u++) pa[u] = *reinterpret_cast<const unsigned int*>(featb + sa[u] * 128 + c0);
#pragma unroll
      for (int u = 0; u < 8; u++) wa[u] = *reinterpret_cast<const f32x4*>(ws_s + (off0 + i + u) * 4);
      for (int c = 1; c < nfull; c++){
        int sb[8]; unsigned int pb[8]; f32x4 wb[8];
#pragma unroll
        for (int u = 0; u < 8; u++) sb[u] = __shfl(ssrc, c * 8 + u);
#pragma unroll
        for (int u = 0; u < 8; u++) pb[u] = *reinterpret_cast<const unsigned int*>(featb + sb[u] * 128 + c0);
#pragma unroll
        for (int u = 0; u < 8; u++) wb[u] = *reinterpret_cast<const f32x4*>(ws_s + (off0 + i + c * 8 + u) * 4);
#pragma unroll
        for (int u = 0; u < 8; u++) FMA1(wa[u], pa[u]);
#pragma unroll
        for (int u = 0; u < 8; u++){ pa[u] = pb[u]; wa[u] = wb[u]; }
      }
#pragma unroll
      for (int u = 0; u < 8; u++) FMA1(wa[u], pa[u]);
    }
    for (int j = nfull * 8; j < blk; j++){
      int s = __shfl(ssrc, j);
      unsigned int pv = *reinterpret_cast<const unsigned int*>(featb + s * 128 + c0);
      f32x4 wv = *reinterpret_cast<const f32x4*>(ws_s + (off0 + i + j) * 4);
      FMA1(wv, pv);
    }
    i += blk;
  }

  // reduce denominator across lanes (once per node)
#pragma unroll
  for (int o = 32; o >= 1; o >>= 1){
#pragma unroll
    for (int h = 0; h < 4; h++) wsum[h] += __shfl_xor(wsum[h], o);
  }
  f32x4 rd;
#pragma unroll
  for (int h = 0; h < 4; h++) rd[h] = (wsum[h] > 0.f) ? 1.0f / wsum[h] : 0.f;
#pragma unroll
  for (int h = 0; h < 4; h++){
    unsigned int ov = (unsigned int)f2b(acc2[h][0] * rd[h]) |
                      ((unsigned int)f2b(acc2[h][1] * rd[h]) << 16);
    *reinterpret_cast<unsigned int*>(fagg + n * 512 + h * 128 + c0) = ov;
  }
}

// ---- combined GEMM + fused BN stats ----
// rst = F_agg @ Wfc + feat @ Wres + bias -> comb bf16, then each block
// re-reads its OWN 128x128 tile (L2-hot, k_stats access pattern), LDS-reduces
// (no shuffles -- r5 lesson), and atomicAdds per-channel partials to gsum/gsq.
__global__ __launch_bounds__(512) void k_gemmC(const unsigned short* __restrict__ fagg,
                                               const unsigned short* __restrict__ featb,
                                               const unsigned short* __restrict__ Wt2s,
                                               const float* __restrict__ bias,
                                               unsigned short* __restrict__ comb,
                                               float* __restrict__ gsum,
                                               float* __restrict__ gsq){
  __shared__ unsigned short wsl[2 * 128 * 128];   // 64KB: both K-phases (+stats reuse)
  char* wb = (char*)wsl;
  int tid = threadIdx.x;
  int wave = tid >> 6, lane = tid & 63;
  int lrow = lane & 15, quad = lane >> 4;
  int rowbase = blockIdx.x * 128 + wave * 16;
  int colbase = blockIdx.y * 128;             // by = head index (0..3)
  int arow = rowbase + lrow; if (arow > N_ - 1) arow = N_ - 1;
  const unsigned short* aF = fagg + arow * 512 + colbase;   // head slice
  const unsigned short* aX = featb + arow * 128;
#pragma unroll
  for (int ph = 0; ph < 2; ph++){
    const unsigned short* gt = Wt2s + (((ph << 2) | (int)blockIdx.y) << 14);
#pragma unroll
    for (int i = 0; i < 4; i++){
      int off = ((i << 3) | wave) << 9;   // 1KB chunks
      gl_lds16(gt + off + (lane << 3), wsl + (ph << 14) + off);
    }
  }
  __syncthreads();
  f32x4 acc[8] = {};
#pragma unroll
  for (int ph = 0; ph < 2; ph++){
#pragma unroll
    for (int kk = 0; kk < 4; kk++){
      Frag a;
      a.q = (ph == 0)
          ? *reinterpret_cast<const u32x4*>(aF + kk * 32 + quad * 8)
          : *reinterpret_cast<const u32x4*>(aX + kk * 32 + quad * 8);
#pragma unroll
      for (int s = 0; s < 8; s++){
        int r = s * 16 + lrow;
        int byte = (ph << 15) + ((r * 256 + kk * 64 + quad * 16) ^ ((r & 7) << 4));
        Frag b; b.q = *reinterpret_cast<const u32x4*>(wb + byte);
        acc[s] = __builtin_amdgcn_mfma_f32_16x16x32_bf16(b.v, a.v, acc[s], 0, 0, 0);
      }
    }
  }
  int gr = rowbase + lrow;
  if (gr < N_){
    unsigned short* crow = comb + gr * 512 + colbase;
#pragma unroll
    for (int s = 0; s < 8; s++){
      f32x4 bb = *reinterpret_cast<const f32x4*>(bias + colbase + s * 16 + quad * 4);
      u32x2 ov;
#pragma unroll
      for (int d = 0; d < 2; d++){
        float v0 = acc[s][2 * d]     + bb[2 * d];
        float v1 = acc[s][2 * d + 1] + bb[2 * d + 1];
        ov[d] = (unsigned int)f2b(v0) | ((unsigned int)f2b(v1) << 16);
      }
      *reinterpret_cast<u32x2*>(crow + s * 16 + quad * 4) = ov;
    }
  }
  // ---- fused BN stats over this block's tile ----
  __syncthreads();    // drains vmcnt: C-writes visible; wsl free for reuse
  {
    int cg = tid & 15;          // channel group: 8 chans at colbase + cg*8
    int rs = tid >> 4;          // row-set 0..31: rows rowbase0 + rs*4 ..+4
    int rowbase0 = blockIdx.x * 128;
    float s[8] = {}, q[8] = {};
#pragma unroll
    for (int rr2 = 0; rr2 < 4; rr2++){
      int r = rowbase0 + rs * 4 + rr2;
      if (r < N_){
        u32x4 pv = *reinterpret_cast<const u32x4*>(comb + r * 512 + colbase + cg * 8);
#pragma unroll
        for (int d = 0; d < 4; d++){
          float v0 = blo(pv[d]);
          float v1 = bhi(pv[d]);
          s[2*d]   += v0; q[2*d]   += v0 * v0;
          s[2*d+1] += v1; q[2*d+1] += v1 * v1;
        }
      }
    }
    float* Ls = (float*)wsl;            // [32][128]
    float* Lq = (float*)wsl + 4096;     // [32][128]
#pragma unroll
    for (int d = 0; d < 8; d += 4){
      *reinterpret_cast<f32x4*>(&Ls[rs * 128 + cg * 8 + d]) = *reinterpret_cast<f32x4*>(&s[d]);
      *reinterpret_cast<f32x4*>(&Lq[rs * 128 + cg * 8 + d]) = *reinterpret_cast<f32x4*>(&q[d]);
    }
    __syncthreads();
    if (tid < 256){
      int ch = tid & 127;
      const float* B = (tid < 128) ? Ls : Lq;
      float a = 0.f;
#pragma unroll 8
      for (int r2 = 0; r2 < 32; r2++) a += B[r2 * 128 + ch];
      float* gp = (tid < 128) ? (gsum + colbase + ch) : (gsq + colbase + ch);
      atomicAdd(gp, a);
    }
  }
}

// ---- GEMM2: out = relu(BN(comb)) @ Wout + bout, fp32 out ----
// scale/shift computed inline from gsum/gsq.
__global__ __launch_bounds__(256) void k_gemm2(const unsigned short* __restrict__ comb,
                                               const unsigned short* __restrict__ WtOuts,
                                               const float* __restrict__ gsum,
                                               const float* __restrict__ gsq,
                                               const float* __restrict__ gamma,
                                               const float* __restrict__ beta,
                                               const float* __restrict__ bout,
                                               float* __restrict__ out){
  __shared__ float sc[512], sh[512];
  __shared__ unsigned short wsl[128 * 128];   // 32KB
  char* wb = (char*)wsl;
  int t = threadIdx.x;
  for (int i = t; i < 512; i += 256){
    float sum = gsum[i], sq = gsq[i];
    float mu  = sum * (1.0f / (float)N_);
    float var = sq * (1.0f / (float)N_) - mu * mu;
    float inv = rsqrtf(var + 1e-5f);
    float scv = gamma[i] * inv;
    sc[i] = scv;
    sh[i] = beta[i] - mu * scv;
  }
  int wave = t >> 6, lane = t & 63, lrow = lane & 15, quad = lane >> 4;
  int rowbase = blockIdx.x * 64 + wave * 16;
  int rr = rowbase + lrow; if (rr > N_ - 1) rr = N_ - 1;
  const unsigned short* arow = comb + rr * 512;
  f32x4 acc[8] = {};
  for (int phase = 0; phase < 4; phase++){
    __syncthreads();
    {
      const unsigned short* gt = WtOuts + (phase << 14);
#pragma unroll
      for (int i = 0; i < 8; i++){
        int off = ((i << 2) | wave) << 9;
        gl_lds16(gt + off + (lane << 3), wsl + off);
      }
    }
    __syncthreads();
#pragma unroll
    for (int kk = 0; kk < 4; kk++){
      int base = phase * 128 + kk * 32 + quad * 8;
      Frag a; a.q = *reinterpret_cast<const u32x4*>(arow + base);
#pragma unroll
      for (int i2 = 0; i2 < 8; i2++){
        float x = b2f(a.us[i2]);
        x = fmaf(x, sc[base + i2], sh[base + i2]);
        a.us[i2] = f2b(fmaxf(x, 0.0f));
      }
#pragma unroll
      for (int s = 0; s < 8; s++){
        int r = s * 16 + lrow;
        int byte = (r * 256 + kk * 64 + quad * 16) ^ ((r & 7) << 4);
        Frag b; b.q = *reinterpret_cast<const u32x4*>(wb + byte);
        acc[s] = __builtin_amdgcn_mfma_f32_16x16x32_bf16(b.v, a.v, acc[s], 0, 0, 0);
      }
    }
  }
  int gr = rowbase + lrow;
  if (gr < N_){
    float* orow = out + gr * 128;
#pragma unroll
    for (int s = 0; s < 8; s++){
      int cb = s * 16 + quad * 4;
      f32x4 bb = *reinterpret_cast<const f32x4*>(bout + cb);
      f32x4 ov;
#pragma unroll
      for (int j = 0; j < 4; j++) ov[j] = acc[s][j] + bb[j];
      *reinterpret_cast<f32x4*>(orow + cb) = ov;
    }
  }
}

extern "C" void kernel_launch(void* const* d_in, const int* in_sizes, int n_in,
                              void* d_out, int out_size, void* d_ws, size_t ws_size,
                              hipStream_t stream){
  const float* feat  = (const float*)d_in[0];
  const int*   src   = (const int*)d_in[1];
  const int*   dst   = (const int*)d_in[2];
  const float* Wfc   = (const float*)d_in[3];
  const float* al    = (const float*)d_in[4];
  const float* ar    = (const float*)d_in[5];
  const float* Wres  = (const float*)d_in[6];
  const float* bias  = (const float*)d_in[7];
  const float* gamma = (const float*)d_in[8];
  const float* beta  = (const float*)d_in[9];
  const float* Wout  = (const float*)d_in[10];
  const float* bout  = (const float*)d_in[11];
  float* out = (float*)d_out;

  char* ws = (char*)d_ws;
  unsigned short* comb  = (unsigned short*)(ws + 0);           // 30,720,000
  unsigned short* fagg  = (unsigned short*)(ws + 30720000);    // 30,720,000
  unsigned short* Wt2s  = (unsigned short*)(ws + 61440000);    //    262,144
  unsigned short* WtOuts= (unsigned short*)(ws + 61702144);    //    131,072
  float*          el    = (float*)(ws + 61833216);             //    480,000
  float*          er    = (float*)(ws + 62313216);             //    480,000
  float*          ws_s  = (float*)(ws + 62793216);             //  7,680,000
  int*            offs  = (int*)(ws + 70473216);               //    120,064
  int*            counts= (int*)(ws + 70593280);               //    120,000
  int*            cursor= (int*)(ws + 70713280);               //    120,000
  int*            src_s = (int*)(ws + 70833280);               //  1,920,000
  float*          Pbuf  = (float*)(ws + 72753280);             //      8,192 (P)
  float*          gsum  = (float*)(ws + 73801856);             //      2,048 (512 f32)
  float*          gsq   = (float*)(ws + 73803904);             //      2,048 (512 f32)
  unsigned short* featb = (unsigned short*)(ws + 73805952);    //  7,680,000

  k_initconv<<<260, 256, 0, stream>>>(Wfc, Wres, Wout, al, ar, Wt2s, WtOuts, Pbuf,
                                      counts, cursor, gsum, gsq);
  k_elhist<<<1875 + (N_ + 31) / 32, 256, 0, stream>>>(feat, Pbuf, dst, counts,
                                                      el, er, featb);
  k_scan<<<1, 1024, 0, stream>>>(counts, offs);
  k_edge<<<(E_ + 255) / 256, 256, 0, stream>>>(src, dst, el, er, ws_s, src_s, offs, cursor);
  k_aggrf<<<(N_ + 3) / 4, 256, 0, stream>>>(offs, src_s, ws_s, featb, fagg);
  dim3 gC((N_ + 127) / 128, 4);
  k_gemmC<<<gC, 512, 0, stream>>>(fagg, featb, Wt2s, bias, comb, gsum, gsq);
  k_gemm2<<<(N_ + 63) / 64, 256, 0, stream>>>(comb, WtOuts, gsum, gsq, gamma, beta,
                                              bout, out);
}